// Round 15
// baseline (1012.451 us; speedup 1.0000x reference)
//
#include <hip/hip_runtime.h>
#include <math.h>

#define NB 32
#define NT 512
#define ND 256
#define NH 4
#define NLAYER 6
#define TOUT 2048

typedef __attribute__((ext_vector_type(8))) short bf16x8;
typedef __attribute__((ext_vector_type(4))) float f32x4;
typedef __attribute__((ext_vector_type(16))) float f32x16;

static __device__ __forceinline__ unsigned short f2b(float f) {
    union { float f; unsigned int u; } x; x.f = f;
    unsigned int u = x.u;
    return (unsigned short)((u + 0x7FFFu + ((u >> 16) & 1u)) >> 16);
}
static __device__ __forceinline__ float b2f(unsigned short s) {
    union { unsigned int u; float f; } x; x.u = ((unsigned int)s) << 16;
    return x.f;
}

// bank-balanced 16B-block swizzle for 32-short rows (4 blocks)
#define SW(r) (((r) >> 1) & 3)

// direct global->LDS DMA, 16B per lane; LDS dest = wave-uniform base + lane*16
static __device__ __forceinline__ void gload16(const void* g, void* l) {
    __builtin_amdgcn_global_load_lds(
        (const __attribute__((address_space(1))) unsigned int*)g,
        (__attribute__((address_space(3))) unsigned int*)l, 16, 0, 0);
}

// ---------------- workspace layout (float offsets) ----------------
#define OFF_X    0ull          // x fp32 [B,T,256] (residual)
#define OFF_FFH  4194304ull    // ffh bf16 [16384,1024]; later d1b bf16
#define OFF_WBT  12582912ull   // transformer weights bf16 [N][K]
#define OFF_CWT  14942208ull   // conv weights bf16 (884736 sh) + xtb bf16 mirror (at +4194304 sh)
#define OFF_QKV  20971520ull   // qkv bf16 + vt bf16; later reg bf16
#define OFF_ATTN 33554432ull   // attn out bf16 / dp h1 bf16 (1st half) + xb bf16 (2nd half); later d2b bf16
#define OFF_PROJ 37748736ull   // dp h2 fp32
#define OFF_INT  41951232ull   // ints: dur, tok

// ---------------- embedding + positional encoding ----------------
__global__ __launch_bounds__(256) void embed_kernel(const int* __restrict__ text,
                                                    const float* __restrict__ emb,
                                                    float* __restrict__ x,
                                                    unsigned short* __restrict__ xtb)
{
    const int row = blockIdx.x;
    const int d = threadIdx.x;
    const int t = row & (NT - 1);
    const int id = text[row];
    const int j2 = (d >> 1) * 2;
    const float c = -9.210340371976184f / 256.0f;
    float freq = expf((float)j2 * c);
    float ang = (float)t * freq;
    float pe = (d & 1) ? cosf(ang) : sinf(ang);
    float v = emb[(size_t)id * ND + d] + pe;
    x[(size_t)row * ND + d] = v;
    xtb[(size_t)row * ND + d] = f2b(v);
}

// ---------------- merged transformer weight transpose: fp32 [K,N] -> bf16 [N,K] ----------------
__global__ __launch_bounds__(256) void wqall_kernel(const float* __restrict__ Wqkv,
                                                    const float* __restrict__ Wo,
                                                    const float* __restrict__ W1,
                                                    const float* __restrict__ W2,
                                                    unsigned short* __restrict__ Wbt)
{
    __shared__ float tile[32][33];
    const int tt = blockIdx.x, layer = blockIdx.y;
    const float* src; int K, N, n0, k0, inLS; size_t outSeg;
    if (tt < 192)      { src = Wqkv; K = 256;  N = 768;  n0 = (tt % 24) * 32; k0 = (tt / 24) * 32; inLS = 196608; outSeg = 0; }
    else if (tt < 256) { int t2 = tt - 192; src = Wo; K = 256; N = 256;  n0 = (t2 & 7) * 32;  k0 = (t2 >> 3) * 32; inLS = 65536;  outSeg = 196608; }
    else if (tt < 512) { int t3 = tt - 256; src = W1; K = 256; N = 1024; n0 = (t3 & 31) * 32; k0 = (t3 >> 5) * 32; inLS = 262144; outSeg = 262144; }
    else               { int t4 = tt - 512; src = W2; K = 1024; N = 256; n0 = (t4 & 7) * 32;  k0 = (t4 >> 3) * 32; inLS = 262144; outSeg = 524288; }
    const float* Wl = src + (size_t)layer * inLS;
    unsigned short* ol = Wbt + (size_t)layer * 786432 + outSeg;
    const int tx = threadIdx.x & 31, ty = threadIdx.x >> 5;
#pragma unroll
    for (int j = 0; j < 4; ++j)
        tile[ty + j * 8][tx] = Wl[(size_t)(k0 + ty + j * 8) * N + n0 + tx];
    __syncthreads();
#pragma unroll
    for (int j = 0; j < 4; ++j)
        ol[(size_t)(n0 + ty + j * 8) * K + k0 + tx] = f2b(tile[tx][ty + j * 8]);
}

// ---------------- merged conv weight transpose: w[O,I,K] -> wtb[k][o][c] bf16 ----------------
__global__ __launch_bounds__(256) void wtransball_kernel(const float* __restrict__ dp_w1,
                                                         const float* __restrict__ dp_w2,
                                                         const float* __restrict__ dec_w1,
                                                         const float* __restrict__ dec_w2,
                                                         unsigned short* __restrict__ cw)
{
    int gid = blockIdx.x * 256 + threadIdx.x;
    if (gid >= 884736) return;
    const float* src; int CIN = 256, COUT, KS, idx;
    if (gid < 196608)      { src = dp_w1;  COUT = 256; KS = 3; idx = gid; }
    else if (gid < 393216) { src = dp_w2;  COUT = 256; KS = 3; idx = gid - 196608; }
    else if (gid < 720896) { src = dec_w1; COUT = 256; KS = 5; idx = gid - 393216; }
    else                   { src = dec_w2; COUT = 128; KS = 5; idx = gid - 720896; }
    int c = idx % CIN;
    int r = idx / CIN;
    int o = r % COUT;
    int k = r / COUT;
    cw[gid] = f2b(src[(o * CIN + c) * KS + k]);
}

// ---------------- bf16 MFMA GEMM (qkv / ff1): C = A @ B + bias, A bf16, BK=64 ----------------
template<int NTILE, bool RELU, bool CBF16, bool VOUT>
__global__ __launch_bounds__(256) void gemmbf_kernel(const unsigned short* __restrict__ Ab,
                                                     const unsigned short* __restrict__ Bt,
                                                     const float* __restrict__ bias,
                                                     void* __restrict__ C_,
                                                     unsigned short* __restrict__ vt,
                                                     int M, int N, int K)
{
    constexpr int MT = 2;   // NTILE == 128
    __shared__ __align__(16) unsigned short Asb[128 * 64];
    __shared__ __align__(16) unsigned short Bsb[NTILE * 64];
    const int tid = threadIdx.x;
    const int lane = tid & 63, wave = tid >> 6;
    const int ln = lane & 31, hi = lane >> 5;
    const int row0 = blockIdx.y * 128, col0 = blockIdx.x * NTILE;
    const int mOff = (wave >> 1) * 64;
    const int nOff = (wave & 1) * 64;
    float* Cf = (float*)C_;
    unsigned short* Cb = (unsigned short*)C_;
    f32x16 acc[MT][2] = {};

    for (int k0 = 0; k0 < K; k0 += 64) {
#pragma unroll
        for (int j = 0; j < 4; ++j) {           // A: 128 rows, 16 calls
            int c = wave * 4 + j;
            int m = c * 8 + (lane >> 3);
            int bg = (lane & 7) ^ (m & 7);
            gload16(&Ab[(size_t)(row0 + m) * K + k0 + bg * 8],
                    &Asb[c * 8 * 64]);
        }
#pragma unroll
        for (int j = 0; j < NTILE / 32; ++j) {  // B: NTILE rows
            int c = wave * (NTILE / 32) + j;
            int n = c * 8 + (lane >> 3);
            int bg = (lane & 7) ^ (n & 7);
            gload16(&Bt[(size_t)(col0 + n) * K + k0 + bg * 8],
                    &Bsb[c * 8 * 64]);
        }
        __syncthreads();
#pragma unroll
        for (int kh = 0; kh < 4; ++kh) {
            const int kb = kh * 2 + hi;
            bf16x8 af[MT], bfr[2];
#pragma unroll
            for (int mt = 0; mt < MT; ++mt) {
                int r = mOff + mt * 32 + ln;
                af[mt] = *(const bf16x8*)&Asb[r * 64 + ((kb ^ (r & 7)) << 3)];
            }
#pragma unroll
            for (int nt = 0; nt < 2; ++nt) {
                int r = nOff + nt * 32 + ln;
                bfr[nt] = *(const bf16x8*)&Bsb[r * 64 + ((kb ^ (r & 7)) << 3)];
            }
#pragma unroll
            for (int mt = 0; mt < MT; ++mt)
#pragma unroll
                for (int nt = 0; nt < 2; ++nt)
                    acc[mt][nt] = __builtin_amdgcn_mfma_f32_32x32x16_bf16(
                        af[mt], bfr[nt], acc[mt][nt], 0, 0, 0);
        }
        __syncthreads();
    }
#pragma unroll
    for (int mt = 0; mt < MT; ++mt)
#pragma unroll
        for (int nt = 0; nt < 2; ++nt) {
            int col = col0 + nOff + nt * 32 + ln;
            float bi = bias[col];
#pragma unroll
            for (int g = 0; g < 4; ++g) {
                unsigned short s4[4];
#pragma unroll
                for (int r4 = 0; r4 < 4; ++r4) {
                    int row = row0 + mOff + mt * 32 + hi * 4 + g * 8 + r4;
                    float v = acc[mt][nt][g * 4 + r4] + bi;
                    if (RELU) v = fmaxf(v, 0.f);
                    if (CBF16) { s4[r4] = f2b(v); Cb[(size_t)row * N + col] = s4[r4]; }
                    else       Cf[(size_t)row * N + col] = v;
                }
                if (VOUT && col >= 512) {
                    int rowg = row0 + mOff + mt * 32 + hi * 4 + g * 8;
                    int b = rowg >> 9, t = rowg & (NT - 1);
                    int hh = (col - 512) >> 6, dd = (col - 512) & 63;
                    *(uint2*)&vt[((size_t)(b * NH + hh) * 64 + dd) * NT + t] = *(uint2*)s4;
                }
            }
        }
}

// ---------------- bf16 MFMA GEMM + residual + LayerNorm (proj / ff2), BK=128 ----------------
__global__ __launch_bounds__(256) void gemmln_kernel(const unsigned short* __restrict__ A,
                                                     const unsigned short* __restrict__ Bt,
                                                     const float* __restrict__ bias,
                                                     const float* __restrict__ lng,
                                                     const float* __restrict__ lnb,
                                                     float* __restrict__ x,
                                                     unsigned short* __restrict__ xtb,
                                                     int K)
{
    __shared__ __align__(16) unsigned short Asb[32 * 128];
    __shared__ __align__(16) unsigned short Bsb[256 * 128];
    __shared__ float sred[32][4][2];
    const int tid = threadIdx.x;
    const int lane = tid & 63, wave = tid >> 6;
    const int ln = lane & 31, hi = lane >> 5;
    const int row0 = blockIdx.x * 32;
    const int colbase = wave * 64;
    f32x16 acc[2] = {};

    for (int k0 = 0; k0 < K; k0 += 128) {
#pragma unroll
        for (int j = 0; j < 2; ++j) {   // stage A: 32 rows, 8 calls (2/wave), 4 rows/call
            int c = wave * 2 + j;
            int m = c * 4 + (lane >> 4);
            int bg = (lane & 15) ^ (m & 15);
            gload16(&A[(size_t)(row0 + m) * K + k0 + bg * 8],
                    &Asb[c * 4 * 128]);
        }
#pragma unroll
        for (int j = 0; j < 16; ++j) {  // stage B: 256 rows, 64 calls (16/wave)
            int c = wave * 16 + j;
            int n = c * 4 + (lane >> 4);
            int bg = (lane & 15) ^ (n & 15);
            gload16(&Bt[(size_t)n * K + k0 + bg * 8],
                    &Bsb[c * 4 * 128]);
        }
        __syncthreads();
#pragma unroll
        for (int kh = 0; kh < 8; ++kh) {
            const int kb = kh * 2 + hi;
            int r = ln;
            bf16x8 af = *(const bf16x8*)&Asb[r * 128 + ((kb ^ (r & 15)) << 3)];
#pragma unroll
            for (int nt = 0; nt < 2; ++nt) {
                int rb = colbase + nt * 32 + ln;
                bf16x8 bfr = *(const bf16x8*)&Bsb[rb * 128 + ((kb ^ (rb & 15)) << 3)];
                acc[nt] = __builtin_amdgcn_mfma_f32_32x32x16_bf16(af, bfr, acc[nt], 0, 0, 0);
            }
        }
        __syncthreads();
    }

    // epilogue: u = acc + bias + x; LN across 256 cols (4 waves per row)
    float bi[2], gv[2], bv[2];
#pragma unroll
    for (int nt = 0; nt < 2; ++nt) {
        int col = colbase + nt * 32 + ln;
        bi[nt] = bias[col]; gv[nt] = lng[col]; bv[nt] = lnb[col];
    }
#pragma unroll
    for (int g = 0; g < 4; ++g)
#pragma unroll
        for (int r4 = 0; r4 < 4; ++r4) {
            int rl = hi * 4 + g * 8 + r4;
            size_t base = (size_t)(row0 + rl) * ND + colbase + ln;
#pragma unroll
            for (int nt = 0; nt < 2; ++nt)
                acc[nt][g * 4 + r4] += bi[nt] + x[base + nt * 32];
        }
#pragma unroll
    for (int g = 0; g < 4; ++g)
#pragma unroll
        for (int r4 = 0; r4 < 4; ++r4) {
            int i = g * 4 + r4;
            float ps = acc[0][i] + acc[1][i];
            float ps2 = acc[0][i] * acc[0][i] + acc[1][i] * acc[1][i];
#pragma unroll
            for (int o = 1; o < 32; o <<= 1) {
                ps += __shfl_xor(ps, o);
                ps2 += __shfl_xor(ps2, o);
            }
            if (ln == 0) {
                int rl = hi * 4 + g * 8 + r4;
                sred[rl][wave][0] = ps;
                sred[rl][wave][1] = ps2;
            }
        }
    __syncthreads();
#pragma unroll
    for (int g = 0; g < 4; ++g)
#pragma unroll
        for (int r4 = 0; r4 < 4; ++r4) {
            int i = g * 4 + r4;
            int rl = hi * 4 + g * 8 + r4;
            float s  = sred[rl][0][0] + sred[rl][1][0] + sred[rl][2][0] + sred[rl][3][0];
            float s2 = sred[rl][0][1] + sred[rl][1][1] + sred[rl][2][1] + sred[rl][3][1];
            float m = s * (1.0f / 256.0f);
            float var = fmaxf(s2 * (1.0f / 256.0f) - m * m, 0.0f);
            float rinv = 1.0f / sqrtf(var + 1e-5f);
            size_t base = (size_t)(row0 + rl) * ND + colbase + ln;
#pragma unroll
            for (int nt = 0; nt < 2; ++nt) {
                float v = (acc[nt][i] - m) * rinv * gv[nt] + bv[nt];
                x[base + nt * 32] = v;
                xtb[base + nt * 32] = f2b(v);
            }
        }
}

// ---------------- attention v11: K AND V staged once per block via global_load_lds ----------------
// V rows (256B contiguous in vt) DMA-coalesced -> kills the 4x-redundant per-wave
// scatter loads. Same chunk timing (L2-locality invariant preserved). LDS 64KB, 2 blocks/CU.
__global__ __launch_bounds__(256, 2) void attn3_kernel(const unsigned short* __restrict__ qkv,
                                                       const unsigned short* __restrict__ vt,
                                                       unsigned short* __restrict__ out)
{
    __shared__ __align__(16) unsigned short sP[4][32 * 128];
    __shared__ __align__(16) unsigned short sK[128 * 64];
    __shared__ __align__(16) unsigned short sV[64 * 128];
    const int tid = threadIdx.x;
    const int lane = tid & 63, wave = tid >> 6;
    const int ln = lane & 31, hi = lane >> 5;
    const int h = blockIdx.y, b = blockIdx.z;
    const int q0 = blockIdx.x * 128 + wave * 32;
    const size_t base = (size_t)b * NT * 768;
    const int qoff = h * 64;
    const unsigned short* vbh = vt + (size_t)(b * NH + h) * 64 * NT;

    bf16x8 qf[4];
#pragma unroll
    for (int s = 0; s < 4; ++s)
        qf[s] = *(const bf16x8*)&qkv[base + (size_t)(q0 + ln) * 768 + qoff + s * 16 + hi * 8];

    f32x16 oacc[2] = {};
    f32x16 lacc = {};
    bf16x8 onev;
#pragma unroll
    for (int j = 0; j < 8; ++j) onev[j] = (short)0x3F80;   // bf16 1.0
    const float sc = 0.18033688011112042f;   // 0.125 * log2(e)
    unsigned short* Pw = &sP[wave][0];

    for (int ch = 0; ch < 4; ++ch) {
        const int s0 = ch * 128;
        // stage K chunk (128 rows x 64 d): 16 calls, 4/wave; row=128B=8 blocks
#pragma unroll
        for (int j = 0; j < 4; ++j) {
            int c = wave + 4 * j;
            int rl = c * 8 + (lane >> 3);
            int bg = (lane & 7) ^ (rl & 7);
            gload16(&qkv[base + (size_t)(s0 + rl) * 768 + 256 + qoff + bg * 8],
                    &sK[c * 8 * 64]);
        }
        // stage V chunk (64 d x 128 t): 16 calls, 4/wave; row=256B=16 blocks, contiguous
#pragma unroll
        for (int j = 0; j < 4; ++j) {
            int c = wave + 4 * j;
            int d = c * 4 + (lane >> 4);
            int bg = (lane & 15) ^ (d & 15);
            gload16(&vbh[(size_t)d * NT + s0 + bg * 8],
                    &sV[c * 4 * 128]);
        }
        __syncthreads();
        f32x16 sacc[4] = {};
        __builtin_amdgcn_s_setprio(1);
#pragma unroll
        for (int p = 0; p < 4; ++p)
#pragma unroll
            for (int s = 0; s < 4; ++s) {
                int rk = p * 32 + ln;
                bf16x8 kf = *(const bf16x8*)&sK[rk * 64 + (((s * 2 + hi) ^ (rk & 7)) << 3)];
                sacc[p] = __builtin_amdgcn_mfma_f32_32x32x16_bf16(qf[s], kf, sacc[p], 0, 0, 0);
            }
        __builtin_amdgcn_s_setprio(0);
        // P = exp2(clamped scaled score) -- no cross-lane ops at all
#pragma unroll
        for (int i = 0; i < 16; ++i) {
            sacc[0][i] = exp2f(fminf(sacc[0][i] * sc, 80.f));
            sacc[1][i] = exp2f(fminf(sacc[1][i] * sc, 80.f));
            sacc[2][i] = exp2f(fminf(sacc[2][i] * sc, 80.f));
            sacc[3][i] = exp2f(fminf(sacc[3][i] * sc, 80.f));
        }
#pragma unroll
        for (int p = 0; p < 4; ++p) {
            int kb = p * 4 + (ln >> 3), k7 = ln & 7;
#pragma unroll
            for (int i = 0; i < 16; ++i) {
                int q = (i & 3) + 8 * (i >> 2) + 4 * hi;
                Pw[q * 128 + (((kb ^ (q & 7)) << 3) | k7)] = f2b(sacc[p][i]);
            }
        }
        // PV (k = s0 .. s0+127 in two halves) + ones-MFMA row-sum for l; V from sV
        __builtin_amdgcn_s_setprio(1);
#pragma unroll
        for (int s = 0; s < 4; ++s) {
            bf16x8 pf = *(const bf16x8*)&Pw[ln * 128 + (((s * 2 + hi) ^ (ln & 7)) << 3)];
#pragma unroll
            for (int ct = 0; ct < 2; ++ct) {
                int d = ct * 32 + ln;
                bf16x8 vf = *(const bf16x8*)&sV[d * 128 + (((s * 2 + hi) ^ (d & 15)) << 3)];
                oacc[ct] = __builtin_amdgcn_mfma_f32_32x32x16_bf16(vf, pf, oacc[ct], 0, 0, 0);
            }
            lacc = __builtin_amdgcn_mfma_f32_32x32x16_bf16(onev, pf, lacc, 0, 0, 0);
        }
#pragma unroll
        for (int s = 0; s < 4; ++s) {
            bf16x8 pf = *(const bf16x8*)&Pw[ln * 128 + (((8 + s * 2 + hi) ^ (ln & 7)) << 3)];
#pragma unroll
            for (int ct = 0; ct < 2; ++ct) {
                int d = ct * 32 + ln;
                bf16x8 vf = *(const bf16x8*)&sV[d * 128 + (((8 + s * 2 + hi) ^ (d & 15)) << 3)];
                oacc[ct] = __builtin_amdgcn_mfma_f32_32x32x16_bf16(vf, pf, oacc[ct], 0, 0, 0);
            }
            lacc = __builtin_amdgcn_mfma_f32_32x32x16_bf16(onev, pf, lacc, 0, 0, 0);
        }
        __builtin_amdgcn_s_setprio(0);
        __syncthreads();   // all waves done with sK/sV before next chunk's staging
    }
    float linv = 1.0f / lacc[0];
    const int q = q0 + ln;
#pragma unroll
    for (int ct = 0; ct < 2; ++ct)
#pragma unroll
        for (int g = 0; g < 4; ++g) {
            unsigned short s4[4];
#pragma unroll
            for (int r4 = 0; r4 < 4; ++r4)
                s4[r4] = f2b(oacc[ct][g * 4 + r4] * linv);
            int d = ct * 32 + g * 8 + 4 * hi;
            *(uint2*)&out[(size_t)(b * NT + q) * ND + qoff + d] = *(uint2*)s4;
        }
}

// ---------------- fused emotion MLP + add: xb = bf16(x + MLP(emotion)[b]) ----------------
__global__ __launch_bounds__(256) void fuse_kernel(const float* __restrict__ emo,
                                                   const float* __restrict__ We1,
                                                   const float* __restrict__ be1,
                                                   const float* __restrict__ We2,
                                                   const float* __restrict__ be2,
                                                   const float* __restrict__ x,
                                                   unsigned short* __restrict__ xb)
{
    const int row = blockIdx.x;
    const int d = threadIdx.x;
    const float em = emo[row >> 9];
    float acc = be2[d];
    for (int j = 0; j < 64; ++j) {
        float h = fmaxf(em * We1[j] + be1[j], 0.0f);
        acc = fmaf(h, We2[j * ND + d], acc);
    }
    xb[(size_t)row * ND + d] = f2b(x[(size_t)row * ND + d] + acc);
}

// ---------------- unified bf16 MFMA conv: t-tile TT, o-tile ONT*32, wave MT=TT/128 ----------------
template<int CIN, int KS, int TT, int ONT, bool OUT_BF16, bool BN>
__global__ __launch_bounds__(256) void convk_kernel(const unsigned short* __restrict__ inb,
                                                    const unsigned short* __restrict__ wtb,
                                                    const float* __restrict__ bias,
                                                    const float* __restrict__ bng,
                                                    const float* __restrict__ bnb,
                                                    const float* __restrict__ bnm,
                                                    const float* __restrict__ bnv,
                                                    void* __restrict__ out_,
                                                    int T, int COUT)
{
    constexpr int PAD = (KS - 1) / 2;
    constexpr int TEXT = TT + KS - 1;
    constexpr int OTS = ONT * 32;
    constexpr int MT = TT / 128;
    constexpr int BR = KS * OTS;          // B rows
    constexpr int HR = KS - 1;            // halo rows
    __shared__ __align__(16) unsigned short Asb[TEXT * 32];
    __shared__ __align__(16) unsigned short Bsb[BR * 32];
    const int tid = threadIdx.x;
    const int lane = tid & 63, wave = tid >> 6;
    const int ln = lane & 31, hi = lane >> 5;
    const int b = blockIdx.z;
    const int t0 = blockIdx.x * TT;
    const int o0 = blockIdx.y * OTS;
    const int mOff = wave * (MT * 32);
    float* outf = (float*)out_;
    unsigned short* outb = (unsigned short*)out_;
    f32x16 acc[MT][ONT] = {};

    for (int cc = 0; cc < CIN; cc += 32) {
#pragma unroll
        for (int it = 0; it < TT / 64; ++it) {
            int t = PAD + it * 64 + wave * 16 + (lane >> 2);
            int tg = t0 + it * 64 + wave * 16 + (lane >> 2);
            int bg = (lane & 3) ^ SW(t);
            gload16(&inb[((size_t)(b * T) + tg) * CIN + cc + bg * 8],
                    &Asb[(PAD + it * 64 + wave * 16) * 32]);
        }
        if (tid < HR * 4) {
            int hr = tid >> 2, blk = tid & 3;
            int t = (hr < PAD) ? hr : TT + hr;
            int tg = t0 - PAD + t;
            uint4 z = {0u, 0u, 0u, 0u};
            if (tg >= 0 && tg < T)
                z = *(const uint4*)&inb[((size_t)(b * T) + tg) * CIN + cc + blk * 8];
            *(uint4*)&Asb[t * 32 + ((blk ^ SW(t)) << 3)] = z;
        }
#pragma unroll
        for (int c = wave; c < BR / 16; c += 4) {
            int row = c * 16 + (lane >> 2);
            int k = row / OTS, o = row % OTS;
            int bg = (lane & 3) ^ SW(row);
            gload16(&wtb[((size_t)k * COUT + o0 + o) * CIN + cc + bg * 8],
                    &Bsb[c * 16 * 32]);
        }
        __syncthreads();
#pragma unroll
        for (int kh = 0; kh < 2; ++kh) {
            const int kb = kh * 2 + hi;
#pragma unroll
            for (int tap = 0; tap < KS; ++tap) {
                bf16x8 af[MT];
#pragma unroll
                for (int mt = 0; mt < MT; ++mt) {
                    int r = mOff + mt * 32 + ln + tap;
                    af[mt] = *(const bf16x8*)&Asb[r * 32 + ((kb ^ SW(r)) << 3)];
                }
#pragma unroll
                for (int nt = 0; nt < ONT; ++nt) {
                    int rb = tap * OTS + nt * 32 + ln;
                    bf16x8 bfr = *(const bf16x8*)&Bsb[rb * 32 + ((kb ^ SW(rb)) << 3)];
#pragma unroll
                    for (int mt = 0; mt < MT; ++mt)
                        acc[mt][nt] = __builtin_amdgcn_mfma_f32_32x32x16_bf16(
                            af[mt], bfr, acc[mt][nt], 0, 0, 0);
                }
            }
        }
        __syncthreads();
    }
#pragma unroll
    for (int nt = 0; nt < ONT; ++nt) {
        int col = o0 + nt * 32 + ln;
        float bi = bias[col];
        float scv = 1.f, shv = 0.f;
        if (BN) {
            scv = bng[col] / sqrtf(bnv[col] + 1e-5f);
            shv = bnb[col] - bnm[col] * scv;
        }
#pragma unroll
        for (int mt = 0; mt < MT; ++mt)
#pragma unroll
            for (int g = 0; g < 4; ++g)
#pragma unroll
                for (int r4 = 0; r4 < 4; ++r4) {
                    int row = t0 + mOff + mt * 32 + hi * 4 + g * 8 + r4;
                    float v = fmaxf(acc[mt][nt][g * 4 + r4] + bi, 0.f);
                    if (BN) v = v * scv + shv;
                    if (OUT_BF16) outb[((size_t)(b * T) + row) * COUT + col] = f2b(v);
                    else          outf[((size_t)(b * T) + row) * COUT + col] = v;
                }
    }
}

// ---------------- regulated-sequence materialization (bf16 gather) ----------------
__global__ __launch_bounds__(256) void reg_kernel(const unsigned short* __restrict__ xb,
                                                  const int* __restrict__ tok,
                                                  unsigned short* __restrict__ reg)
{
    const int wave = threadIdx.x >> 6, lane = threadIdx.x & 63;
    const int row = blockIdx.x * 4 + wave;
    const int tk = tok[row];
    const int b = row >> 11;
    const int c4 = lane * 4;
    unsigned short s4[4] = {0, 0, 0, 0};
    if (tk >= 0)
        *(uint2*)s4 = *(const uint2*)&xb[((size_t)(b * NT) + tk) * ND + c4];
    *(uint2*)&reg[(size_t)row * ND + c4] = *(uint2*)s4;
}

// ---------------- duration: wave-per-row dot -> dur ----------------
__global__ __launch_bounds__(256) void dur_kernel(const float* __restrict__ h2,
                                                  const float* __restrict__ wo,
                                                  const float* __restrict__ bo,
                                                  int* __restrict__ dur)
{
    const int wave = threadIdx.x >> 6, lane = threadIdx.x & 63;
    const int row = blockIdx.x * 4 + wave;
    const int c4 = lane * 4;
    float4 h = *(const float4*)&h2[(size_t)row * ND + c4];
    float4 w4 = *(const float4*)&wo[c4];
    float s = h.x * w4.x + h.y * w4.y + h.z * w4.z + h.w * w4.w;
#pragma unroll
    for (int o = 1; o < 64; o <<= 1) s += __shfl_xor(s, o);
    if (lane == 0) {
        float d = rintf(expf(s + bo[0]));
        d = fminf(fmaxf(d, 1.0f), 8.0f);
        dur[row] = (int)d;
    }
}

// ---------------- fused scan + token map: parallel block-wide scan ----------------
__global__ __launch_bounds__(256) void scantok_kernel(const int* __restrict__ dur,
                                                      int* __restrict__ tok)
{
    __shared__ int st[NT];
    __shared__ int wsum[4];
    const int b = blockIdx.x, tid = threadIdx.x;
    int v0 = dur[b * NT + 2 * tid];
    int v1 = dur[b * NT + 2 * tid + 1];
    int p = v0 + v1;
    const int lane = tid & 63, w = tid >> 6;
    int x = p;
#pragma unroll
    for (int o = 1; o < 64; o <<= 1) {
        int y = __shfl_up(x, o);
        if (lane >= o) x += y;
    }
    if (lane == 63) wsum[w] = x;
    __syncthreads();
    int add = 0;
#pragma unroll
    for (int k = 0; k < 4; ++k) if (k < w) add += wsum[k];
    int tot = wsum[0] + wsum[1] + wsum[2] + wsum[3];
    int excl = x + add - p;
    st[2 * tid] = excl;
    st[2 * tid + 1] = excl + v0;
    __syncthreads();
    for (int pp = tid; pp < TOUT; pp += 256) {
        int res = -1;
        if (pp < tot) {
            int lo = 0, hi2 = NT - 1;
            while (lo < hi2) {
                int mid = (lo + hi2 + 1) >> 1;
                if (st[mid] <= pp) lo = mid; else hi2 = mid - 1;
            }
            res = lo;
        }
        tok[b * TOUT + pp] = res;
    }
}

// ---------------- decoder conv3: wave-per-output, coalesced ----------------
__global__ __launch_bounds__(256) void conv3_kernel(const unsigned short* __restrict__ in,
                                                    const float* __restrict__ w,
                                                    const float* __restrict__ bias,
                                                    float* __restrict__ out)
{
    const int wave = threadIdx.x >> 6, lane = threadIdx.x & 63;
    const int gid = blockIdx.x * 4 + wave;
    const int b = gid >> 11, t = gid & (TOUT - 1);
    const int c = lane * 2;
    float w0[5], w1[5];
#pragma unroll
    for (int k = 0; k < 5; ++k) { w0[k] = w[c * 5 + k]; w1[k] = w[(c + 1) * 5 + k]; }
    float acc = 0.f;
#pragma unroll
    for (int k = 0; k < 5; ++k) {
        int t2 = t + k - 2;
        if (t2 < 0 || t2 >= TOUT) continue;
        unsigned int u = *(const unsigned int*)&in[((size_t)(b * TOUT) + t2) * 128 + c];
        acc = fmaf(b2f((unsigned short)(u & 0xFFFF)), w0[k], acc);
        acc = fmaf(b2f((unsigned short)(u >> 16)), w1[k], acc);
    }
#pragma unroll
    for (int o = 1; o < 64; o <<= 1) acc += __shfl_xor(acc, o);
    if (lane == 0) out[gid] = acc + bias[0];
}

// ---------------- orchestration ----------------
extern "C" void kernel_launch(void* const* d_in, const int* in_sizes, int n_in,
                              void* d_out, int out_size, void* d_ws, size_t ws_size,
                              hipStream_t stream)
{
    const int*   text    = (const int*)d_in[0];
    const float* emotion = (const float*)d_in[1];
    const float* emb     = (const float*)d_in[2];
    const float* Wqkv    = (const float*)d_in[3];
    const float* bqkv    = (const float*)d_in[4];
    const float* Wo      = (const float*)d_in[5];
    const float* bo      = (const float*)d_in[6];
    const float* W1      = (const float*)d_in[7];
    const float* b1      = (const float*)d_in[8];
    const float* W2      = (const float*)d_in[9];
    const float* b2      = (const float*)d_in[10];
    const float* ln1g    = (const float*)d_in[11];
    const float* ln1b    = (const float*)d_in[12];
    const float* ln2g    = (const float*)d_in[13];
    const float* ln2b    = (const float*)d_in[14];
    const float* We1     = (const float*)d_in[15];
    const float* be1     = (const float*)d_in[16];
    const float* We2     = (const float*)d_in[17];
    const float* be2     = (const float*)d_in[18];
    const float* dp_w1   = (const float*)d_in[19];
    const float* dp_b1   = (const float*)d_in[20];
    const float* dp_g1   = (const float*)d_in[21];
    const float* dp_bt1  = (const float*)d_in[22];
    const float* dp_m1   = (const float*)d_in[23];
    const float* dp_v1   = (const float*)d_in[24];
    const float* dp_w2   = (const float*)d_in[25];
    const float* dp_b2   = (const float*)d_in[26];
    const float* dp_g2   = (const float*)d_in[27];
    const float* dp_bt2  = (const float*)d_in[28];
    const float* dp_m2   = (const float*)d_in[29];
    const float* dp_v2   = (const float*)d_in[30];
    const float* dp_wo   = (const float*)d_in[31];
    const float* dp_bo   = (const float*)d_in[32];
    const float* dec_w3  = (const float*)d_in[37];
    const float* dec_b1  = (const float*)d_in[34];
    const float* dec_b2  = (const float*)d_in[36];
    const float* dec_b3  = (const float*)d_in[38];

    float* ws   = (float*)d_ws;
    float* x    = ws + OFF_X;
    unsigned short* ffhB = (unsigned short*)(ws + OFF_FFH);
    unsigned short* Wbt  = (unsigned short*)(ws + OFF_WBT);
    unsigned short* cw   = (unsigned short*)(ws + OFF_CWT);
    unsigned short* wtbdp1 = cw;
    unsigned short* wtbdp2 = cw + 196608;
    unsigned short* wtb1   = cw + 393216;
    unsigned short* wtb2   = cw + 720896;
    unsigned short* xtb    = cw + 4194304;   // bf16 mirror of x [16384,256]
    unsigned short* qkvB = (unsigned short*)(ws + OFF_QKV);
    unsigned short* vtb  = qkvB + 12582912;
    unsigned short* regB = qkvB;
    float* attb = ws + OFF_ATTN;
    float* prjb = ws + OFF_PROJ;
    unsigned short* attbB = (unsigned short*)attb;
    unsigned short* h1b  = (unsigned short*)attb;
    unsigned short* xbB  = (unsigned short*)attb + 4194304;   // 2nd half of ATTN region
    unsigned short* d1b  = ffhB;
    unsigned short* d2b  = (unsigned short*)attb;
    int*   ip     = (int*)(ws + OFF_INT);
    int*   durb   = ip;
    int*   tokb   = ip + 16384;

    const int M = NB * NT;   // 16384

    embed_kernel<<<M, 256, 0, stream>>>(text, emb, x, xtb);
    wqall_kernel<<<dim3(768, 6), 256, 0, stream>>>(Wqkv, Wo, W1, W2, Wbt);
    wtransball_kernel<<<3456, 256, 0, stream>>>(dp_w1, dp_w2,
                                                (const float*)d_in[33], (const float*)d_in[35], cw);

    for (int l = 0; l < NLAYER; ++l) {
        const unsigned short* WQ  = Wbt + (size_t)l * 786432;
        const unsigned short* WO  = WQ + 196608;
        const unsigned short* WF1 = WQ + 262144;
        const unsigned short* WF2 = WQ + 524288;
        gemmbf_kernel<128, false, true, true><<<dim3(6, 128), 256, 0, stream>>>(
            xtb, WQ, bqkv + l * 768, qkvB, vtb, M, 768, 256);
        attn3_kernel<<<dim3(NT / 128, NH, NB), 256, 0, stream>>>(qkvB, vtb, attbB);
        gemmln_kernel<<<M / 32, 256, 0, stream>>>(
            attbB, WO, bo + l * 256, ln1g + l * ND, ln1b + l * ND, x, xtb, 256);
        gemmbf_kernel<128, true, true, false><<<dim3(8, 128), 256, 0, stream>>>(
            xtb, WF1, b1 + l * 1024, ffhB, nullptr, M, 1024, 256);
        gemmln_kernel<<<M / 32, 256, 0, stream>>>(
            ffhB, WF2, b2 + l * 256, ln2g + l * ND, ln2b + l * ND, x, xtb, 1024);
    }

    fuse_kernel<<<M, 256, 0, stream>>>(emotion, We1, be1, We2, be2, x, xbB);

    // duration predictor convs: t-tile 128 -> 512 blocks (2+ blocks/CU)
    convk_kernel<256, 3, 128, 2, true, true><<<dim3(4, 4, NB), 256, 0, stream>>>(
        xbB, wtbdp1, dp_b1, dp_g1, dp_bt1, dp_m1, dp_v1, h1b, NT, 256);
    convk_kernel<256, 3, 128, 2, false, true><<<dim3(4, 4, NB), 256, 0, stream>>>(
        h1b, wtbdp2, dp_b2, dp_g2, dp_bt2, dp_m2, dp_v2, prjb, NT, 256);
    dur_kernel<<<M / 4, 256, 0, stream>>>(prjb, dp_wo, dp_bo, durb);
    scantok_kernel<<<NB, 256, 0, stream>>>(durb, tokb);

    // decoder: regulated gather then bf16 MFMA convs
    reg_kernel<<<NB * TOUT / 4, 256, 0, stream>>>(xbB, tokb, regB);
    convk_kernel<256, 5, 256, 2, true, false><<<dim3(TOUT / 256, 4, NB), 256, 0, stream>>>(
        regB, wtb1, dec_b1, nullptr, nullptr, nullptr, nullptr, d1b, TOUT, 256);
    convk_kernel<256, 5, 256, 2, true, false><<<dim3(TOUT / 256, 2, NB), 256, 0, stream>>>(
        d1b, wtb2, dec_b2, nullptr, nullptr, nullptr, nullptr, d2b, TOUT, 128);
    conv3_kernel<<<NB * TOUT / 4, 256, 0, stream>>>(d2b, dec_w3, dec_b3, (float*)d_out);
}

// Round 16
// 1001.024 us; speedup vs baseline: 1.0114x; 1.0114x over previous
//
#include <hip/hip_runtime.h>
#include <math.h>

#define NB 32
#define NT 512
#define ND 256
#define NH 4
#define NLAYER 6
#define TOUT 2048

typedef __attribute__((ext_vector_type(8))) short bf16x8;
typedef __attribute__((ext_vector_type(4))) float f32x4;
typedef __attribute__((ext_vector_type(16))) float f32x16;

static __device__ __forceinline__ unsigned short f2b(float f) {
    union { float f; unsigned int u; } x; x.f = f;
    unsigned int u = x.u;
    return (unsigned short)((u + 0x7FFFu + ((u >> 16) & 1u)) >> 16);
}
static __device__ __forceinline__ float b2f(unsigned short s) {
    union { unsigned int u; float f; } x; x.u = ((unsigned int)s) << 16;
    return x.f;
}

// bank-balanced 16B-block swizzle for 32-short rows (4 blocks)
#define SW(r) (((r) >> 1) & 3)

// direct global->LDS DMA, 16B per lane; LDS dest = wave-uniform base + lane*16
static __device__ __forceinline__ void gload16(const void* g, void* l) {
    __builtin_amdgcn_global_load_lds(
        (const __attribute__((address_space(1))) unsigned int*)g,
        (__attribute__((address_space(3))) unsigned int*)l, 16, 0, 0);
}

// ---------------- workspace layout (float offsets) ----------------
#define OFF_X    0ull          // x fp32 [B,T,256] (residual)
#define OFF_FFH  4194304ull    // ffh bf16 [16384,1024]; later d1b bf16
#define OFF_WBT  12582912ull   // transformer weights bf16 [N][K]
#define OFF_CWT  14942208ull   // conv weights bf16 (884736 sh) + xtb bf16 mirror (at +4194304 sh)
#define OFF_QKV  20971520ull   // qkv bf16 + vt bf16; later reg bf16
#define OFF_ATTN 33554432ull   // attn out bf16 / dp h1 bf16 (1st half) + xb bf16 (2nd half); later d2b bf16
#define OFF_PROJ 37748736ull   // dp h2 fp32
#define OFF_INT  41951232ull   // ints: dur, tok

// ---------------- embedding + positional encoding ----------------
__global__ __launch_bounds__(256) void embed_kernel(const int* __restrict__ text,
                                                    const float* __restrict__ emb,
                                                    float* __restrict__ x,
                                                    unsigned short* __restrict__ xtb)
{
    const int row = blockIdx.x;
    const int d = threadIdx.x;
    const int t = row & (NT - 1);
    const int id = text[row];
    const int j2 = (d >> 1) * 2;
    const float c = -9.210340371976184f / 256.0f;
    float freq = expf((float)j2 * c);
    float ang = (float)t * freq;
    float pe = (d & 1) ? cosf(ang) : sinf(ang);
    float v = emb[(size_t)id * ND + d] + pe;
    x[(size_t)row * ND + d] = v;
    xtb[(size_t)row * ND + d] = f2b(v);
}

// ---------------- merged transformer weight transpose: fp32 [K,N] -> bf16 [N,K] ----------------
__global__ __launch_bounds__(256) void wqall_kernel(const float* __restrict__ Wqkv,
                                                    const float* __restrict__ Wo,
                                                    const float* __restrict__ W1,
                                                    const float* __restrict__ W2,
                                                    unsigned short* __restrict__ Wbt)
{
    __shared__ float tile[32][33];
    const int tt = blockIdx.x, layer = blockIdx.y;
    const float* src; int K, N, n0, k0, inLS; size_t outSeg;
    if (tt < 192)      { src = Wqkv; K = 256;  N = 768;  n0 = (tt % 24) * 32; k0 = (tt / 24) * 32; inLS = 196608; outSeg = 0; }
    else if (tt < 256) { int t2 = tt - 192; src = Wo; K = 256; N = 256;  n0 = (t2 & 7) * 32;  k0 = (t2 >> 3) * 32; inLS = 65536;  outSeg = 196608; }
    else if (tt < 512) { int t3 = tt - 256; src = W1; K = 256; N = 1024; n0 = (t3 & 31) * 32; k0 = (t3 >> 5) * 32; inLS = 262144; outSeg = 262144; }
    else               { int t4 = tt - 512; src = W2; K = 1024; N = 256; n0 = (t4 & 7) * 32;  k0 = (t4 >> 3) * 32; inLS = 262144; outSeg = 524288; }
    const float* Wl = src + (size_t)layer * inLS;
    unsigned short* ol = Wbt + (size_t)layer * 786432 + outSeg;
    const int tx = threadIdx.x & 31, ty = threadIdx.x >> 5;
#pragma unroll
    for (int j = 0; j < 4; ++j)
        tile[ty + j * 8][tx] = Wl[(size_t)(k0 + ty + j * 8) * N + n0 + tx];
    __syncthreads();
#pragma unroll
    for (int j = 0; j < 4; ++j)
        ol[(size_t)(n0 + ty + j * 8) * K + k0 + tx] = f2b(tile[tx][ty + j * 8]);
}

// ---------------- merged conv weight transpose: w[O,I,K] -> wtb[k][o][c] bf16 ----------------
__global__ __launch_bounds__(256) void wtransball_kernel(const float* __restrict__ dp_w1,
                                                         const float* __restrict__ dp_w2,
                                                         const float* __restrict__ dec_w1,
                                                         const float* __restrict__ dec_w2,
                                                         unsigned short* __restrict__ cw)
{
    int gid = blockIdx.x * 256 + threadIdx.x;
    if (gid >= 884736) return;
    const float* src; int CIN = 256, COUT, KS, idx;
    if (gid < 196608)      { src = dp_w1;  COUT = 256; KS = 3; idx = gid; }
    else if (gid < 393216) { src = dp_w2;  COUT = 256; KS = 3; idx = gid - 196608; }
    else if (gid < 720896) { src = dec_w1; COUT = 256; KS = 5; idx = gid - 393216; }
    else                   { src = dec_w2; COUT = 128; KS = 5; idx = gid - 720896; }
    int c = idx % CIN;
    int r = idx / CIN;
    int o = r % COUT;
    int k = r / COUT;
    cw[gid] = f2b(src[(o * CIN + c) * KS + k]);
}

// ---------------- bf16 MFMA GEMM (qkv / ff1): C = A @ B + bias, A bf16, BK=64 ----------------
template<int NTILE, bool RELU, bool CBF16, bool VOUT>
__global__ __launch_bounds__(256) void gemmbf_kernel(const unsigned short* __restrict__ Ab,
                                                     const unsigned short* __restrict__ Bt,
                                                     const float* __restrict__ bias,
                                                     void* __restrict__ C_,
                                                     unsigned short* __restrict__ vt,
                                                     int M, int N, int K)
{
    constexpr int MT = 2;   // NTILE == 128
    __shared__ __align__(16) unsigned short Asb[128 * 64];
    __shared__ __align__(16) unsigned short Bsb[NTILE * 64];
    const int tid = threadIdx.x;
    const int lane = tid & 63, wave = tid >> 6;
    const int ln = lane & 31, hi = lane >> 5;
    const int row0 = blockIdx.y * 128, col0 = blockIdx.x * NTILE;
    const int mOff = (wave >> 1) * 64;
    const int nOff = (wave & 1) * 64;
    float* Cf = (float*)C_;
    unsigned short* Cb = (unsigned short*)C_;
    f32x16 acc[MT][2] = {};

    for (int k0 = 0; k0 < K; k0 += 64) {
#pragma unroll
        for (int j = 0; j < 4; ++j) {           // A: 128 rows, 16 calls
            int c = wave * 4 + j;
            int m = c * 8 + (lane >> 3);
            int bg = (lane & 7) ^ (m & 7);
            gload16(&Ab[(size_t)(row0 + m) * K + k0 + bg * 8],
                    &Asb[c * 8 * 64]);
        }
#pragma unroll
        for (int j = 0; j < NTILE / 32; ++j) {  // B: NTILE rows
            int c = wave * (NTILE / 32) + j;
            int n = c * 8 + (lane >> 3);
            int bg = (lane & 7) ^ (n & 7);
            gload16(&Bt[(size_t)(col0 + n) * K + k0 + bg * 8],
                    &Bsb[c * 8 * 64]);
        }
        __syncthreads();
#pragma unroll
        for (int kh = 0; kh < 4; ++kh) {
            const int kb = kh * 2 + hi;
            bf16x8 af[MT], bfr[2];
#pragma unroll
            for (int mt = 0; mt < MT; ++mt) {
                int r = mOff + mt * 32 + ln;
                af[mt] = *(const bf16x8*)&Asb[r * 64 + ((kb ^ (r & 7)) << 3)];
            }
#pragma unroll
            for (int nt = 0; nt < 2; ++nt) {
                int r = nOff + nt * 32 + ln;
                bfr[nt] = *(const bf16x8*)&Bsb[r * 64 + ((kb ^ (r & 7)) << 3)];
            }
#pragma unroll
            for (int mt = 0; mt < MT; ++mt)
#pragma unroll
                for (int nt = 0; nt < 2; ++nt)
                    acc[mt][nt] = __builtin_amdgcn_mfma_f32_32x32x16_bf16(
                        af[mt], bfr[nt], acc[mt][nt], 0, 0, 0);
        }
        __syncthreads();
    }
#pragma unroll
    for (int mt = 0; mt < MT; ++mt)
#pragma unroll
        for (int nt = 0; nt < 2; ++nt) {
            int col = col0 + nOff + nt * 32 + ln;
            float bi = bias[col];
#pragma unroll
            for (int g = 0; g < 4; ++g) {
                unsigned short s4[4];
#pragma unroll
                for (int r4 = 0; r4 < 4; ++r4) {
                    int row = row0 + mOff + mt * 32 + hi * 4 + g * 8 + r4;
                    float v = acc[mt][nt][g * 4 + r4] + bi;
                    if (RELU) v = fmaxf(v, 0.f);
                    if (CBF16) { s4[r4] = f2b(v); Cb[(size_t)row * N + col] = s4[r4]; }
                    else       Cf[(size_t)row * N + col] = v;
                }
                if (VOUT && col >= 512) {
                    int rowg = row0 + mOff + mt * 32 + hi * 4 + g * 8;
                    int b = rowg >> 9, t = rowg & (NT - 1);
                    int hh = (col - 512) >> 6, dd = (col - 512) & 63;
                    *(uint2*)&vt[((size_t)(b * NH + hh) * 64 + dd) * NT + t] = *(uint2*)s4;
                }
            }
        }
}

// ---------------- bf16 MFMA GEMM + residual + LayerNorm (proj / ff2), BK=128 ----------------
__global__ __launch_bounds__(256) void gemmln_kernel(const unsigned short* __restrict__ A,
                                                     const unsigned short* __restrict__ Bt,
                                                     const float* __restrict__ bias,
                                                     const float* __restrict__ lng,
                                                     const float* __restrict__ lnb,
                                                     float* __restrict__ x,
                                                     unsigned short* __restrict__ xtb,
                                                     int K)
{
    __shared__ __align__(16) unsigned short Asb[32 * 128];
    __shared__ __align__(16) unsigned short Bsb[256 * 128];
    __shared__ float sred[32][4][2];
    const int tid = threadIdx.x;
    const int lane = tid & 63, wave = tid >> 6;
    const int ln = lane & 31, hi = lane >> 5;
    const int row0 = blockIdx.x * 32;
    const int colbase = wave * 64;
    f32x16 acc[2] = {};

    for (int k0 = 0; k0 < K; k0 += 128) {
#pragma unroll
        for (int j = 0; j < 2; ++j) {   // stage A: 32 rows, 8 calls (2/wave), 4 rows/call
            int c = wave * 2 + j;
            int m = c * 4 + (lane >> 4);
            int bg = (lane & 15) ^ (m & 15);
            gload16(&A[(size_t)(row0 + m) * K + k0 + bg * 8],
                    &Asb[c * 4 * 128]);
        }
#pragma unroll
        for (int j = 0; j < 16; ++j) {  // stage B: 256 rows, 64 calls (16/wave)
            int c = wave * 16 + j;
            int n = c * 4 + (lane >> 4);
            int bg = (lane & 15) ^ (n & 15);
            gload16(&Bt[(size_t)n * K + k0 + bg * 8],
                    &Bsb[c * 4 * 128]);
        }
        __syncthreads();
#pragma unroll
        for (int kh = 0; kh < 8; ++kh) {
            const int kb = kh * 2 + hi;
            int r = ln;
            bf16x8 af = *(const bf16x8*)&Asb[r * 128 + ((kb ^ (r & 15)) << 3)];
#pragma unroll
            for (int nt = 0; nt < 2; ++nt) {
                int rb = colbase + nt * 32 + ln;
                bf16x8 bfr = *(const bf16x8*)&Bsb[rb * 128 + ((kb ^ (rb & 15)) << 3)];
                acc[nt] = __builtin_amdgcn_mfma_f32_32x32x16_bf16(af, bfr, acc[nt], 0, 0, 0);
            }
        }
        __syncthreads();
    }

    // epilogue: u = acc + bias + x; LN across 256 cols (4 waves per row)
    float bi[2], gv[2], bv[2];
#pragma unroll
    for (int nt = 0; nt < 2; ++nt) {
        int col = colbase + nt * 32 + ln;
        bi[nt] = bias[col]; gv[nt] = lng[col]; bv[nt] = lnb[col];
    }
#pragma unroll
    for (int g = 0; g < 4; ++g)
#pragma unroll
        for (int r4 = 0; r4 < 4; ++r4) {
            int rl = hi * 4 + g * 8 + r4;
            size_t base = (size_t)(row0 + rl) * ND + colbase + ln;
#pragma unroll
            for (int nt = 0; nt < 2; ++nt)
                acc[nt][g * 4 + r4] += bi[nt] + x[base + nt * 32];
        }
#pragma unroll
    for (int g = 0; g < 4; ++g)
#pragma unroll
        for (int r4 = 0; r4 < 4; ++r4) {
            int i = g * 4 + r4;
            float ps = acc[0][i] + acc[1][i];
            float ps2 = acc[0][i] * acc[0][i] + acc[1][i] * acc[1][i];
#pragma unroll
            for (int o = 1; o < 32; o <<= 1) {
                ps += __shfl_xor(ps, o);
                ps2 += __shfl_xor(ps2, o);
            }
            if (ln == 0) {
                int rl = hi * 4 + g * 8 + r4;
                sred[rl][wave][0] = ps;
                sred[rl][wave][1] = ps2;
            }
        }
    __syncthreads();
#pragma unroll
    for (int g = 0; g < 4; ++g)
#pragma unroll
        for (int r4 = 0; r4 < 4; ++r4) {
            int i = g * 4 + r4;
            int rl = hi * 4 + g * 8 + r4;
            float s  = sred[rl][0][0] + sred[rl][1][0] + sred[rl][2][0] + sred[rl][3][0];
            float s2 = sred[rl][0][1] + sred[rl][1][1] + sred[rl][2][1] + sred[rl][3][1];
            float m = s * (1.0f / 256.0f);
            float var = fmaxf(s2 * (1.0f / 256.0f) - m * m, 0.0f);
            float rinv = 1.0f / sqrtf(var + 1e-5f);
            size_t base = (size_t)(row0 + rl) * ND + colbase + ln;
#pragma unroll
            for (int nt = 0; nt < 2; ++nt) {
                float v = (acc[nt][i] - m) * rinv * gv[nt] + bv[nt];
                x[base + nt * 32] = v;
                xtb[base + nt * 32] = f2b(v);
            }
        }
}

// ---------------- attention v10 (R14-exact): K staged once per block; V in registers ----------------
// V loads are latency-hidden (V0 under exp, V1 under PV0) -- R15 measured that LDS-staging
// V regresses (serializes behind barrier + lengthens PV dep chain). Keep K-LDS / V-reg split.
__global__ __launch_bounds__(256, 2) void attn3_kernel(const unsigned short* __restrict__ qkv,
                                                       const unsigned short* __restrict__ vt,
                                                       unsigned short* __restrict__ out)
{
    __shared__ __align__(16) unsigned short sP[4][32 * 128];
    __shared__ __align__(16) unsigned short sK[128 * 64];
    const int tid = threadIdx.x;
    const int lane = tid & 63, wave = tid >> 6;
    const int ln = lane & 31, hi = lane >> 5;
    const int h = blockIdx.y, b = blockIdx.z;
    const int q0 = blockIdx.x * 128 + wave * 32;
    const size_t base = (size_t)b * NT * 768;
    const int qoff = h * 64;
    const unsigned short* vbh = vt + (size_t)(b * NH + h) * 64 * NT;

    bf16x8 qf[4];
#pragma unroll
    for (int s = 0; s < 4; ++s)
        qf[s] = *(const bf16x8*)&qkv[base + (size_t)(q0 + ln) * 768 + qoff + s * 16 + hi * 8];

    f32x16 oacc[2] = {};
    f32x16 lacc = {};
    bf16x8 onev;
#pragma unroll
    for (int j = 0; j < 8; ++j) onev[j] = (short)0x3F80;   // bf16 1.0
    const float sc = 0.18033688011112042f;   // 0.125 * log2(e)
    unsigned short* Pw = &sP[wave][0];

    for (int ch = 0; ch < 4; ++ch) {
        const int s0 = ch * 128;
#pragma unroll
        for (int j = 0; j < 4; ++j) {
            int c = wave + 4 * j;
            int rl = c * 8 + (lane >> 3);
            int bg = (lane & 7) ^ (rl & 7);
            gload16(&qkv[base + (size_t)(s0 + rl) * 768 + 256 + qoff + bg * 8],
                    &sK[c * 8 * 64]);
        }
        __syncthreads();
        f32x16 sacc[4] = {};
        __builtin_amdgcn_s_setprio(1);
#pragma unroll
        for (int p = 0; p < 4; ++p)
#pragma unroll
            for (int s = 0; s < 4; ++s) {
                int rk = p * 32 + ln;
                bf16x8 kf = *(const bf16x8*)&sK[rk * 64 + (((s * 2 + hi) ^ (rk & 7)) << 3)];
                sacc[p] = __builtin_amdgcn_mfma_f32_32x32x16_bf16(qf[s], kf, sacc[p], 0, 0, 0);
            }
        __builtin_amdgcn_s_setprio(0);
        bf16x8 vfr[2][4];
#pragma unroll
        for (int ct = 0; ct < 2; ++ct)
#pragma unroll
            for (int s = 0; s < 4; ++s)
                vfr[ct][s] = *(const bf16x8*)&vbh[(size_t)(ct * 32 + ln) * NT + s0 + s * 16 + hi * 8];
#pragma unroll
        for (int i = 0; i < 16; ++i) {
            sacc[0][i] = exp2f(fminf(sacc[0][i] * sc, 80.f));
            sacc[1][i] = exp2f(fminf(sacc[1][i] * sc, 80.f));
            sacc[2][i] = exp2f(fminf(sacc[2][i] * sc, 80.f));
            sacc[3][i] = exp2f(fminf(sacc[3][i] * sc, 80.f));
        }
#pragma unroll
        for (int p = 0; p < 4; ++p) {
            int kb = p * 4 + (ln >> 3), k7 = ln & 7;
#pragma unroll
            for (int i = 0; i < 16; ++i) {
                int q = (i & 3) + 8 * (i >> 2) + 4 * hi;
                Pw[q * 128 + (((kb ^ (q & 7)) << 3) | k7)] = f2b(sacc[p][i]);
            }
        }
        __builtin_amdgcn_s_setprio(1);
#pragma unroll
        for (int s = 0; s < 4; ++s) {
            bf16x8 pf = *(const bf16x8*)&Pw[ln * 128 + (((s * 2 + hi) ^ (ln & 7)) << 3)];
#pragma unroll
            for (int ct = 0; ct < 2; ++ct)
                oacc[ct] = __builtin_amdgcn_mfma_f32_32x32x16_bf16(vfr[ct][s], pf, oacc[ct], 0, 0, 0);
            lacc = __builtin_amdgcn_mfma_f32_32x32x16_bf16(onev, pf, lacc, 0, 0, 0);
        }
        __builtin_amdgcn_s_setprio(0);
#pragma unroll
        for (int ct = 0; ct < 2; ++ct)
#pragma unroll
            for (int s = 0; s < 4; ++s)
                vfr[ct][s] = *(const bf16x8*)&vbh[(size_t)(ct * 32 + ln) * NT + s0 + 64 + s * 16 + hi * 8];
        __builtin_amdgcn_s_setprio(1);
#pragma unroll
        for (int s = 0; s < 4; ++s) {
            bf16x8 pf = *(const bf16x8*)&Pw[ln * 128 + (((8 + s * 2 + hi) ^ (ln & 7)) << 3)];
#pragma unroll
            for (int ct = 0; ct < 2; ++ct)
                oacc[ct] = __builtin_amdgcn_mfma_f32_32x32x16_bf16(vfr[ct][s], pf, oacc[ct], 0, 0, 0);
            lacc = __builtin_amdgcn_mfma_f32_32x32x16_bf16(onev, pf, lacc, 0, 0, 0);
        }
        __builtin_amdgcn_s_setprio(0);
        __syncthreads();   // all waves done with sK before next chunk's staging
    }
    float linv = 1.0f / lacc[0];
    const int q = q0 + ln;
#pragma unroll
    for (int ct = 0; ct < 2; ++ct)
#pragma unroll
        for (int g = 0; g < 4; ++g) {
            unsigned short s4[4];
#pragma unroll
            for (int r4 = 0; r4 < 4; ++r4)
                s4[r4] = f2b(oacc[ct][g * 4 + r4] * linv);
            int d = ct * 32 + g * 8 + 4 * hi;
            *(uint2*)&out[(size_t)(b * NT + q) * ND + qoff + d] = *(uint2*)s4;
        }
}

// ---------------- fused emotion MLP + add: xb = bf16(x + MLP(emotion)[b]) ----------------
__global__ __launch_bounds__(256) void fuse_kernel(const float* __restrict__ emo,
                                                   const float* __restrict__ We1,
                                                   const float* __restrict__ be1,
                                                   const float* __restrict__ We2,
                                                   const float* __restrict__ be2,
                                                   const float* __restrict__ x,
                                                   unsigned short* __restrict__ xb)
{
    const int row = blockIdx.x;
    const int d = threadIdx.x;
    const float em = emo[row >> 9];
    float acc = be2[d];
    for (int j = 0; j < 64; ++j) {
        float h = fmaxf(em * We1[j] + be1[j], 0.0f);
        acc = fmaf(h, We2[j * ND + d], acc);
    }
    xb[(size_t)row * ND + d] = f2b(x[(size_t)row * ND + d] + acc);
}

// ---------------- unified bf16 MFMA conv: t-tile TT, o-tile ONT*32, wave MT=TT/128 ----------------
template<int CIN, int KS, int TT, int ONT, bool OUT_BF16, bool BN>
__global__ __launch_bounds__(256) void convk_kernel(const unsigned short* __restrict__ inb,
                                                    const unsigned short* __restrict__ wtb,
                                                    const float* __restrict__ bias,
                                                    const float* __restrict__ bng,
                                                    const float* __restrict__ bnb,
                                                    const float* __restrict__ bnm,
                                                    const float* __restrict__ bnv,
                                                    void* __restrict__ out_,
                                                    int T, int COUT)
{
    constexpr int PAD = (KS - 1) / 2;
    constexpr int TEXT = TT + KS - 1;
    constexpr int OTS = ONT * 32;
    constexpr int MT = TT / 128;
    constexpr int BR = KS * OTS;          // B rows
    constexpr int HR = KS - 1;            // halo rows
    __shared__ __align__(16) unsigned short Asb[TEXT * 32];
    __shared__ __align__(16) unsigned short Bsb[BR * 32];
    const int tid = threadIdx.x;
    const int lane = tid & 63, wave = tid >> 6;
    const int ln = lane & 31, hi = lane >> 5;
    const int b = blockIdx.z;
    const int t0 = blockIdx.x * TT;
    const int o0 = blockIdx.y * OTS;
    const int mOff = wave * (MT * 32);
    float* outf = (float*)out_;
    unsigned short* outb = (unsigned short*)out_;
    f32x16 acc[MT][ONT] = {};

    for (int cc = 0; cc < CIN; cc += 32) {
#pragma unroll
        for (int it = 0; it < TT / 64; ++it) {
            int t = PAD + it * 64 + wave * 16 + (lane >> 2);
            int tg = t0 + it * 64 + wave * 16 + (lane >> 2);
            int bg = (lane & 3) ^ SW(t);
            gload16(&inb[((size_t)(b * T) + tg) * CIN + cc + bg * 8],
                    &Asb[(PAD + it * 64 + wave * 16) * 32]);
        }
        if (tid < HR * 4) {
            int hr = tid >> 2, blk = tid & 3;
            int t = (hr < PAD) ? hr : TT + hr;
            int tg = t0 - PAD + t;
            uint4 z = {0u, 0u, 0u, 0u};
            if (tg >= 0 && tg < T)
                z = *(const uint4*)&inb[((size_t)(b * T) + tg) * CIN + cc + blk * 8];
            *(uint4*)&Asb[t * 32 + ((blk ^ SW(t)) << 3)] = z;
        }
#pragma unroll
        for (int c = wave; c < BR / 16; c += 4) {
            int row = c * 16 + (lane >> 2);
            int k = row / OTS, o = row % OTS;
            int bg = (lane & 3) ^ SW(row);
            gload16(&wtb[((size_t)k * COUT + o0 + o) * CIN + cc + bg * 8],
                    &Bsb[c * 16 * 32]);
        }
        __syncthreads();
#pragma unroll
        for (int kh = 0; kh < 2; ++kh) {
            const int kb = kh * 2 + hi;
#pragma unroll
            for (int tap = 0; tap < KS; ++tap) {
                bf16x8 af[MT];
#pragma unroll
                for (int mt = 0; mt < MT; ++mt) {
                    int r = mOff + mt * 32 + ln + tap;
                    af[mt] = *(const bf16x8*)&Asb[r * 32 + ((kb ^ SW(r)) << 3)];
                }
#pragma unroll
                for (int nt = 0; nt < ONT; ++nt) {
                    int rb = tap * OTS + nt * 32 + ln;
                    bf16x8 bfr = *(const bf16x8*)&Bsb[rb * 32 + ((kb ^ SW(rb)) << 3)];
#pragma unroll
                    for (int mt = 0; mt < MT; ++mt)
                        acc[mt][nt] = __builtin_amdgcn_mfma_f32_32x32x16_bf16(
                            af[mt], bfr, acc[mt][nt], 0, 0, 0);
                }
            }
        }
        __syncthreads();
    }
#pragma unroll
    for (int nt = 0; nt < ONT; ++nt) {
        int col = o0 + nt * 32 + ln;
        float bi = bias[col];
        float scv = 1.f, shv = 0.f;
        if (BN) {
            scv = bng[col] / sqrtf(bnv[col] + 1e-5f);
            shv = bnb[col] - bnm[col] * scv;
        }
#pragma unroll
        for (int mt = 0; mt < MT; ++mt)
#pragma unroll
            for (int g = 0; g < 4; ++g)
#pragma unroll
                for (int r4 = 0; r4 < 4; ++r4) {
                    int row = t0 + mOff + mt * 32 + hi * 4 + g * 8 + r4;
                    float v = fmaxf(acc[mt][nt][g * 4 + r4] + bi, 0.f);
                    if (BN) v = v * scv + shv;
                    if (OUT_BF16) outb[((size_t)(b * T) + row) * COUT + col] = f2b(v);
                    else          outf[((size_t)(b * T) + row) * COUT + col] = v;
                }
    }
}

// ---------------- regulated-sequence materialization (bf16 gather) ----------------
__global__ __launch_bounds__(256) void reg_kernel(const unsigned short* __restrict__ xb,
                                                  const int* __restrict__ tok,
                                                  unsigned short* __restrict__ reg)
{
    const int wave = threadIdx.x >> 6, lane = threadIdx.x & 63;
    const int row = blockIdx.x * 4 + wave;
    const int tk = tok[row];
    const int b = row >> 11;
    const int c4 = lane * 4;
    unsigned short s4[4] = {0, 0, 0, 0};
    if (tk >= 0)
        *(uint2*)s4 = *(const uint2*)&xb[((size_t)(b * NT) + tk) * ND + c4];
    *(uint2*)&reg[(size_t)row * ND + c4] = *(uint2*)s4;
}

// ---------------- duration: wave-per-row dot -> dur ----------------
__global__ __launch_bounds__(256) void dur_kernel(const float* __restrict__ h2,
                                                  const float* __restrict__ wo,
                                                  const float* __restrict__ bo,
                                                  int* __restrict__ dur)
{
    const int wave = threadIdx.x >> 6, lane = threadIdx.x & 63;
    const int row = blockIdx.x * 4 + wave;
    const int c4 = lane * 4;
    float4 h = *(const float4*)&h2[(size_t)row * ND + c4];
    float4 w4 = *(const float4*)&wo[c4];
    float s = h.x * w4.x + h.y * w4.y + h.z * w4.z + h.w * w4.w;
#pragma unroll
    for (int o = 1; o < 64; o <<= 1) s += __shfl_xor(s, o);
    if (lane == 0) {
        float d = rintf(expf(s + bo[0]));
        d = fminf(fmaxf(d, 1.0f), 8.0f);
        dur[row] = (int)d;
    }
}

// ---------------- fused scan + token map: parallel block-wide scan ----------------
__global__ __launch_bounds__(256) void scantok_kernel(const int* __restrict__ dur,
                                                      int* __restrict__ tok)
{
    __shared__ int st[NT];
    __shared__ int wsum[4];
    const int b = blockIdx.x, tid = threadIdx.x;
    int v0 = dur[b * NT + 2 * tid];
    int v1 = dur[b * NT + 2 * tid + 1];
    int p = v0 + v1;
    const int lane = tid & 63, w = tid >> 6;
    int x = p;
#pragma unroll
    for (int o = 1; o < 64; o <<= 1) {
        int y = __shfl_up(x, o);
        if (lane >= o) x += y;
    }
    if (lane == 63) wsum[w] = x;
    __syncthreads();
    int add = 0;
#pragma unroll
    for (int k = 0; k < 4; ++k) if (k < w) add += wsum[k];
    int tot = wsum[0] + wsum[1] + wsum[2] + wsum[3];
    int excl = x + add - p;
    st[2 * tid] = excl;
    st[2 * tid + 1] = excl + v0;
    __syncthreads();
    for (int pp = tid; pp < TOUT; pp += 256) {
        int res = -1;
        if (pp < tot) {
            int lo = 0, hi2 = NT - 1;
            while (lo < hi2) {
                int mid = (lo + hi2 + 1) >> 1;
                if (st[mid] <= pp) lo = mid; else hi2 = mid - 1;
            }
            res = lo;
        }
        tok[b * TOUT + pp] = res;
    }
}

// ---------------- decoder conv3: wave-per-output, coalesced ----------------
__global__ __launch_bounds__(256) void conv3_kernel(const unsigned short* __restrict__ in,
                                                    const float* __restrict__ w,
                                                    const float* __restrict__ bias,
                                                    float* __restrict__ out)
{
    const int wave = threadIdx.x >> 6, lane = threadIdx.x & 63;
    const int gid = blockIdx.x * 4 + wave;
    const int b = gid >> 11, t = gid & (TOUT - 1);
    const int c = lane * 2;
    float w0[5], w1[5];
#pragma unroll
    for (int k = 0; k < 5; ++k) { w0[k] = w[c * 5 + k]; w1[k] = w[(c + 1) * 5 + k]; }
    float acc = 0.f;
#pragma unroll
    for (int k = 0; k < 5; ++k) {
        int t2 = t + k - 2;
        if (t2 < 0 || t2 >= TOUT) continue;
        unsigned int u = *(const unsigned int*)&in[((size_t)(b * TOUT) + t2) * 128 + c];
        acc = fmaf(b2f((unsigned short)(u & 0xFFFF)), w0[k], acc);
        acc = fmaf(b2f((unsigned short)(u >> 16)), w1[k], acc);
    }
#pragma unroll
    for (int o = 1; o < 64; o <<= 1) acc += __shfl_xor(acc, o);
    if (lane == 0) out[gid] = acc + bias[0];
}

// ---------------- orchestration ----------------
extern "C" void kernel_launch(void* const* d_in, const int* in_sizes, int n_in,
                              void* d_out, int out_size, void* d_ws, size_t ws_size,
                              hipStream_t stream)
{
    const int*   text    = (const int*)d_in[0];
    const float* emotion = (const float*)d_in[1];
    const float* emb     = (const float*)d_in[2];
    const float* Wqkv    = (const float*)d_in[3];
    const float* bqkv    = (const float*)d_in[4];
    const float* Wo      = (const float*)d_in[5];
    const float* bo      = (const float*)d_in[6];
    const float* W1      = (const float*)d_in[7];
    const float* b1      = (const float*)d_in[8];
    const float* W2      = (const float*)d_in[9];
    const float* b2      = (const float*)d_in[10];
    const float* ln1g    = (const float*)d_in[11];
    const float* ln1b    = (const float*)d_in[12];
    const float* ln2g    = (const float*)d_in[13];
    const float* ln2b    = (const float*)d_in[14];
    const float* We1     = (const float*)d_in[15];
    const float* be1     = (const float*)d_in[16];
    const float* We2     = (const float*)d_in[17];
    const float* be2     = (const float*)d_in[18];
    const float* dp_w1   = (const float*)d_in[19];
    const float* dp_b1   = (const float*)d_in[20];
    const float* dp_g1   = (const float*)d_in[21];
    const float* dp_bt1  = (const float*)d_in[22];
    const float* dp_m1   = (const float*)d_in[23];
    const float* dp_v1   = (const float*)d_in[24];
    const float* dp_w2   = (const float*)d_in[25];
    const float* dp_b2   = (const float*)d_in[26];
    const float* dp_g2   = (const float*)d_in[27];
    const float* dp_bt2  = (const float*)d_in[28];
    const float* dp_m2   = (const float*)d_in[29];
    const float* dp_v2   = (const float*)d_in[30];
    const float* dp_wo   = (const float*)d_in[31];
    const float* dp_bo   = (const float*)d_in[32];
    const float* dec_w3  = (const float*)d_in[37];
    const float* dec_b1  = (const float*)d_in[34];
    const float* dec_b2  = (const float*)d_in[36];
    const float* dec_b3  = (const float*)d_in[38];

    float* ws   = (float*)d_ws;
    float* x    = ws + OFF_X;
    unsigned short* ffhB = (unsigned short*)(ws + OFF_FFH);
    unsigned short* Wbt  = (unsigned short*)(ws + OFF_WBT);
    unsigned short* cw   = (unsigned short*)(ws + OFF_CWT);
    unsigned short* wtbdp1 = cw;
    unsigned short* wtbdp2 = cw + 196608;
    unsigned short* wtb1   = cw + 393216;
    unsigned short* wtb2   = cw + 720896;
    unsigned short* xtb    = cw + 4194304;   // bf16 mirror of x [16384,256]
    unsigned short* qkvB = (unsigned short*)(ws + OFF_QKV);
    unsigned short* vtb  = qkvB + 12582912;
    unsigned short* regB = qkvB;
    float* attb = ws + OFF_ATTN;
    float* prjb = ws + OFF_PROJ;
    unsigned short* attbB = (unsigned short*)attb;
    unsigned short* h1b  = (unsigned short*)attb;
    unsigned short* xbB  = (unsigned short*)attb + 4194304;   // 2nd half of ATTN region
    unsigned short* d1b  = ffhB;
    unsigned short* d2b  = (unsigned short*)attb;
    int*   ip     = (int*)(ws + OFF_INT);
    int*   durb   = ip;
    int*   tokb   = ip + 16384;

    const int M = NB * NT;   // 16384

    embed_kernel<<<M, 256, 0, stream>>>(text, emb, x, xtb);
    wqall_kernel<<<dim3(768, 6), 256, 0, stream>>>(Wqkv, Wo, W1, W2, Wbt);
    wtransball_kernel<<<3456, 256, 0, stream>>>(dp_w1, dp_w2,
                                                (const float*)d_in[33], (const float*)d_in[35], cw);

    for (int l = 0; l < NLAYER; ++l) {
        const unsigned short* WQ  = Wbt + (size_t)l * 786432;
        const unsigned short* WO  = WQ + 196608;
        const unsigned short* WF1 = WQ + 262144;
        const unsigned short* WF2 = WQ + 524288;
        gemmbf_kernel<128, false, true, true><<<dim3(6, 128), 256, 0, stream>>>(
            xtb, WQ, bqkv + l * 768, qkvB, vtb, M, 768, 256);
        attn3_kernel<<<dim3(NT / 128, NH, NB), 256, 0, stream>>>(qkvB, vtb, attbB);
        gemmln_kernel<<<M / 32, 256, 0, stream>>>(
            attbB, WO, bo + l * 256, ln1g + l * ND, ln1b + l * ND, x, xtb, 256);
        gemmbf_kernel<128, true, true, false><<<dim3(8, 128), 256, 0, stream>>>(
            xtb, WF1, b1 + l * 1024, ffhB, nullptr, M, 1024, 256);
        gemmln_kernel<<<M / 32, 256, 0, stream>>>(
            ffhB, WF2, b2 + l * 256, ln2g + l * ND, ln2b + l * ND, x, xtb, 1024);
    }

    fuse_kernel<<<M, 256, 0, stream>>>(emotion, We1, be1, We2, be2, x, xbB);

    // duration predictor convs: t-tile 128 -> 512 blocks (2+ blocks/CU)
    convk_kernel<256, 3, 128, 2, true, true><<<dim3(4, 4, NB), 256, 0, stream>>>(
        xbB, wtbdp1, dp_b1, dp_g1, dp_bt1, dp_m1, dp_v1, h1b, NT, 256);
    convk_kernel<256, 3, 128, 2, false, true><<<dim3(4, 4, NB), 256, 0, stream>>>(
        h1b, wtbdp2, dp_b2, dp_g2, dp_bt2, dp_m2, dp_v2, prjb, NT, 256);
    dur_kernel<<<M / 4, 256, 0, stream>>>(prjb, dp_wo, dp_bo, durb);
    scantok_kernel<<<NB, 256, 0, stream>>>(durb, tokb);

    // decoder: regulated gather then bf16 MFMA convs
    reg_kernel<<<NB * TOUT / 4, 256, 0, stream>>>(xbB, tokb, regB);
    convk_kernel<256, 5, 256, 2, true, false><<<dim3(TOUT / 256, 4, NB), 256, 0, stream>>>(
        regB, wtb1, dec_b1, nullptr, nullptr, nullptr, nullptr, d1b, TOUT, 256);
    convk_kernel<256, 5, 256, 2, true, false><<<dim3(TOUT / 256, 2, NB), 256, 0, stream>>>(
        d1b, wtb2, dec_b2, nullptr, nullptr, nullptr, nullptr, d2b, TOUT, 128);
    conv3_kernel<<<NB * TOUT / 4, 256, 0, stream>>>(d2b, dec_w3, dec_b3, (float*)d_out);
}

// Round 17
// 945.700 us; speedup vs baseline: 1.0706x; 1.0585x over previous
//
#include <hip/hip_runtime.h>
#include <math.h>

#define NB 32
#define NT 512
#define ND 256
#define NH 4
#define NLAYER 6
#define TOUT 2048

typedef __attribute__((ext_vector_type(8))) short bf16x8;
typedef __attribute__((ext_vector_type(4))) float f32x4;
typedef __attribute__((ext_vector_type(16))) float f32x16;

static __device__ __forceinline__ unsigned short f2b(float f) {
    union { float f; unsigned int u; } x; x.f = f;
    unsigned int u = x.u;
    return (unsigned short)((u + 0x7FFFu + ((u >> 16) & 1u)) >> 16);
}
static __device__ __forceinline__ float b2f(unsigned short s) {
    union { unsigned int u; float f; } x; x.u = ((unsigned int)s) << 16;
    return x.f;
}

// bank-balanced 16B-block swizzle for 32-short rows (4 blocks)
#define SW(r) (((r) >> 1) & 3)

// direct global->LDS DMA, 16B per lane; LDS dest = wave-uniform base + lane*16
static __device__ __forceinline__ void gload16(const void* g, void* l) {
    __builtin_amdgcn_global_load_lds(
        (const __attribute__((address_space(1))) unsigned int*)g,
        (__attribute__((address_space(3))) unsigned int*)l, 16, 0, 0);
}

// ---------------- workspace layout (float offsets) ----------------
#define OFF_X    0ull          // x fp32 [B,T,256] (residual)
#define OFF_FFH  4194304ull    // ffh bf16 [16384,1024]; later d1b bf16
#define OFF_WBT  12582912ull   // transformer weights bf16 [N][K]
#define OFF_CWT  14942208ull   // conv weights bf16 (884736 sh) + xtb bf16 mirror (at +4194304 sh)
#define OFF_QKV  20971520ull   // qkv bf16 + vt bf16; later reg bf16
#define OFF_ATTN 33554432ull   // attn out bf16 / dp h1 bf16 (1st half) + xb bf16 (2nd half); later d2b bf16
#define OFF_PROJ 37748736ull   // dp h2 fp32
#define OFF_INT  41951232ull   // ints: dur, tok; then eB fp32 [32,256]

// ---------------- embedding + positional encoding ----------------
__global__ __launch_bounds__(256) void embed_kernel(const int* __restrict__ text,
                                                    const float* __restrict__ emb,
                                                    float* __restrict__ x,
                                                    unsigned short* __restrict__ xtb)
{
    const int row = blockIdx.x;
    const int d = threadIdx.x;
    const int t = row & (NT - 1);
    const int id = text[row];
    const int j2 = (d >> 1) * 2;
    const float c = -9.210340371976184f / 256.0f;
    float freq = expf((float)j2 * c);
    float ang = (float)t * freq;
    float pe = (d & 1) ? cosf(ang) : sinf(ang);
    float v = emb[(size_t)id * ND + d] + pe;
    x[(size_t)row * ND + d] = v;
    xtb[(size_t)row * ND + d] = f2b(v);
}

// ---------------- emotion MLP precompute: e[b][d] (per-batch, computed once) ----------------
__global__ __launch_bounds__(256) void emo_kernel(const float* __restrict__ emo,
                                                  const float* __restrict__ We1,
                                                  const float* __restrict__ be1,
                                                  const float* __restrict__ We2,
                                                  const float* __restrict__ be2,
                                                  float* __restrict__ eB)
{
    const int b = blockIdx.x;
    const int d = threadIdx.x;
    const float em = emo[b];
    float acc = be2[d];
    for (int j = 0; j < 64; ++j) {
        float h = fmaxf(em * We1[j] + be1[j], 0.0f);
        acc = fmaf(h, We2[j * ND + d], acc);
    }
    eB[b * ND + d] = acc;
}

// ---------------- merged transformer weight transpose: fp32 [K,N] -> bf16 [N,K] ----------------
__global__ __launch_bounds__(256) void wqall_kernel(const float* __restrict__ Wqkv,
                                                    const float* __restrict__ Wo,
                                                    const float* __restrict__ W1,
                                                    const float* __restrict__ W2,
                                                    unsigned short* __restrict__ Wbt)
{
    __shared__ float tile[32][33];
    const int tt = blockIdx.x, layer = blockIdx.y;
    const float* src; int K, N, n0, k0, inLS; size_t outSeg;
    if (tt < 192)      { src = Wqkv; K = 256;  N = 768;  n0 = (tt % 24) * 32; k0 = (tt / 24) * 32; inLS = 196608; outSeg = 0; }
    else if (tt < 256) { int t2 = tt - 192; src = Wo; K = 256; N = 256;  n0 = (t2 & 7) * 32;  k0 = (t2 >> 3) * 32; inLS = 65536;  outSeg = 196608; }
    else if (tt < 512) { int t3 = tt - 256; src = W1; K = 256; N = 1024; n0 = (t3 & 31) * 32; k0 = (t3 >> 5) * 32; inLS = 262144; outSeg = 262144; }
    else               { int t4 = tt - 512; src = W2; K = 1024; N = 256; n0 = (t4 & 7) * 32;  k0 = (t4 >> 3) * 32; inLS = 262144; outSeg = 524288; }
    const float* Wl = src + (size_t)layer * inLS;
    unsigned short* ol = Wbt + (size_t)layer * 786432 + outSeg;
    const int tx = threadIdx.x & 31, ty = threadIdx.x >> 5;
#pragma unroll
    for (int j = 0; j < 4; ++j)
        tile[ty + j * 8][tx] = Wl[(size_t)(k0 + ty + j * 8) * N + n0 + tx];
    __syncthreads();
#pragma unroll
    for (int j = 0; j < 4; ++j)
        ol[(size_t)(n0 + ty + j * 8) * K + k0 + tx] = f2b(tile[tx][ty + j * 8]);
}

// ---------------- merged conv weight transpose: w[O,I,K] -> wtb[k][o][c] bf16 ----------------
__global__ __launch_bounds__(256) void wtransball_kernel(const float* __restrict__ dp_w1,
                                                         const float* __restrict__ dp_w2,
                                                         const float* __restrict__ dec_w1,
                                                         const float* __restrict__ dec_w2,
                                                         unsigned short* __restrict__ cw)
{
    int gid = blockIdx.x * 256 + threadIdx.x;
    if (gid >= 884736) return;
    const float* src; int CIN = 256, COUT, KS, idx;
    if (gid < 196608)      { src = dp_w1;  COUT = 256; KS = 3; idx = gid; }
    else if (gid < 393216) { src = dp_w2;  COUT = 256; KS = 3; idx = gid - 196608; }
    else if (gid < 720896) { src = dec_w1; COUT = 256; KS = 5; idx = gid - 393216; }
    else                   { src = dec_w2; COUT = 128; KS = 5; idx = gid - 720896; }
    int c = idx % CIN;
    int r = idx / CIN;
    int o = r % COUT;
    int k = r / COUT;
    cw[gid] = f2b(src[(o * CIN + c) * KS + k]);
}

// ---------------- bf16 MFMA GEMM (qkv / ff1): C = A @ B + bias, A bf16, BK=64 ----------------
template<int NTILE, bool RELU, bool CBF16, bool VOUT>
__global__ __launch_bounds__(256) void gemmbf_kernel(const unsigned short* __restrict__ Ab,
                                                     const unsigned short* __restrict__ Bt,
                                                     const float* __restrict__ bias,
                                                     void* __restrict__ C_,
                                                     unsigned short* __restrict__ vt,
                                                     int M, int N, int K)
{
    constexpr int MT = 2;   // NTILE == 128
    __shared__ __align__(16) unsigned short Asb[128 * 64];
    __shared__ __align__(16) unsigned short Bsb[NTILE * 64];
    const int tid = threadIdx.x;
    const int lane = tid & 63, wave = tid >> 6;
    const int ln = lane & 31, hi = lane >> 5;
    const int row0 = blockIdx.y * 128, col0 = blockIdx.x * NTILE;
    const int mOff = (wave >> 1) * 64;
    const int nOff = (wave & 1) * 64;
    float* Cf = (float*)C_;
    unsigned short* Cb = (unsigned short*)C_;
    f32x16 acc[MT][2] = {};

    for (int k0 = 0; k0 < K; k0 += 64) {
#pragma unroll
        for (int j = 0; j < 4; ++j) {           // A: 128 rows, 16 calls
            int c = wave * 4 + j;
            int m = c * 8 + (lane >> 3);
            int bg = (lane & 7) ^ (m & 7);
            gload16(&Ab[(size_t)(row0 + m) * K + k0 + bg * 8],
                    &Asb[c * 8 * 64]);
        }
#pragma unroll
        for (int j = 0; j < NTILE / 32; ++j) {  // B: NTILE rows
            int c = wave * (NTILE / 32) + j;
            int n = c * 8 + (lane >> 3);
            int bg = (lane & 7) ^ (n & 7);
            gload16(&Bt[(size_t)(col0 + n) * K + k0 + bg * 8],
                    &Bsb[c * 8 * 64]);
        }
        __syncthreads();
#pragma unroll
        for (int kh = 0; kh < 4; ++kh) {
            const int kb = kh * 2 + hi;
            bf16x8 af[MT], bfr[2];
#pragma unroll
            for (int mt = 0; mt < MT; ++mt) {
                int r = mOff + mt * 32 + ln;
                af[mt] = *(const bf16x8*)&Asb[r * 64 + ((kb ^ (r & 7)) << 3)];
            }
#pragma unroll
            for (int nt = 0; nt < 2; ++nt) {
                int r = nOff + nt * 32 + ln;
                bfr[nt] = *(const bf16x8*)&Bsb[r * 64 + ((kb ^ (r & 7)) << 3)];
            }
#pragma unroll
            for (int mt = 0; mt < MT; ++mt)
#pragma unroll
                for (int nt = 0; nt < 2; ++nt)
                    acc[mt][nt] = __builtin_amdgcn_mfma_f32_32x32x16_bf16(
                        af[mt], bfr[nt], acc[mt][nt], 0, 0, 0);
        }
        __syncthreads();
    }
#pragma unroll
    for (int mt = 0; mt < MT; ++mt)
#pragma unroll
        for (int nt = 0; nt < 2; ++nt) {
            int col = col0 + nOff + nt * 32 + ln;
            float bi = bias[col];
#pragma unroll
            for (int g = 0; g < 4; ++g) {
                unsigned short s4[4];
#pragma unroll
                for (int r4 = 0; r4 < 4; ++r4) {
                    int row = row0 + mOff + mt * 32 + hi * 4 + g * 8 + r4;
                    float v = acc[mt][nt][g * 4 + r4] + bi;
                    if (RELU) v = fmaxf(v, 0.f);
                    if (CBF16) { s4[r4] = f2b(v); Cb[(size_t)row * N + col] = s4[r4]; }
                    else       Cf[(size_t)row * N + col] = v;
                }
                if (VOUT && col >= 512) {
                    int rowg = row0 + mOff + mt * 32 + hi * 4 + g * 8;
                    int b = rowg >> 9, t = rowg & (NT - 1);
                    int hh = (col - 512) >> 6, dd = (col - 512) & 63;
                    *(uint2*)&vt[((size_t)(b * NH + hh) * 64 + dd) * NT + t] = *(uint2*)s4;
                }
            }
        }
}

// ---------------- bf16 MFMA GEMM + residual + LayerNorm (proj / ff2), BK=128 ----------------
__global__ __launch_bounds__(256) void gemmln_kernel(const unsigned short* __restrict__ A,
                                                     const unsigned short* __restrict__ Bt,
                                                     const float* __restrict__ bias,
                                                     const float* __restrict__ lng,
                                                     const float* __restrict__ lnb,
                                                     float* __restrict__ x,
                                                     unsigned short* __restrict__ xtb,
                                                     int K)
{
    __shared__ __align__(16) unsigned short Asb[32 * 128];
    __shared__ __align__(16) unsigned short Bsb[256 * 128];
    __shared__ float sred[32][4][2];
    const int tid = threadIdx.x;
    const int lane = tid & 63, wave = tid >> 6;
    const int ln = lane & 31, hi = lane >> 5;
    const int row0 = blockIdx.x * 32;
    const int colbase = wave * 64;
    f32x16 acc[2] = {};

    for (int k0 = 0; k0 < K; k0 += 128) {
#pragma unroll
        for (int j = 0; j < 2; ++j) {   // stage A: 32 rows, 8 calls (2/wave), 4 rows/call
            int c = wave * 2 + j;
            int m = c * 4 + (lane >> 4);
            int bg = (lane & 15) ^ (m & 15);
            gload16(&A[(size_t)(row0 + m) * K + k0 + bg * 8],
                    &Asb[c * 4 * 128]);
        }
#pragma unroll
        for (int j = 0; j < 16; ++j) {  // stage B: 256 rows, 64 calls (16/wave)
            int c = wave * 16 + j;
            int n = c * 4 + (lane >> 4);
            int bg = (lane & 15) ^ (n & 15);
            gload16(&Bt[(size_t)n * K + k0 + bg * 8],
                    &Bsb[c * 4 * 128]);
        }
        __syncthreads();
#pragma unroll
        for (int kh = 0; kh < 8; ++kh) {
            const int kb = kh * 2 + hi;
            int r = ln;
            bf16x8 af = *(const bf16x8*)&Asb[r * 128 + ((kb ^ (r & 15)) << 3)];
#pragma unroll
            for (int nt = 0; nt < 2; ++nt) {
                int rb = colbase + nt * 32 + ln;
                bf16x8 bfr = *(const bf16x8*)&Bsb[rb * 128 + ((kb ^ (rb & 15)) << 3)];
                acc[nt] = __builtin_amdgcn_mfma_f32_32x32x16_bf16(af, bfr, acc[nt], 0, 0, 0);
            }
        }
        __syncthreads();
    }

    // epilogue: u = acc + bias + x; LN across 256 cols (4 waves per row)
    float bi[2], gv[2], bv[2];
#pragma unroll
    for (int nt = 0; nt < 2; ++nt) {
        int col = colbase + nt * 32 + ln;
        bi[nt] = bias[col]; gv[nt] = lng[col]; bv[nt] = lnb[col];
    }
#pragma unroll
    for (int g = 0; g < 4; ++g)
#pragma unroll
        for (int r4 = 0; r4 < 4; ++r4) {
            int rl = hi * 4 + g * 8 + r4;
            size_t base = (size_t)(row0 + rl) * ND + colbase + ln;
#pragma unroll
            for (int nt = 0; nt < 2; ++nt)
                acc[nt][g * 4 + r4] += bi[nt] + x[base + nt * 32];
        }
#pragma unroll
    for (int g = 0; g < 4; ++g)
#pragma unroll
        for (int r4 = 0; r4 < 4; ++r4) {
            int i = g * 4 + r4;
            float ps = acc[0][i] + acc[1][i];
            float ps2 = acc[0][i] * acc[0][i] + acc[1][i] * acc[1][i];
#pragma unroll
            for (int o = 1; o < 32; o <<= 1) {
                ps += __shfl_xor(ps, o);
                ps2 += __shfl_xor(ps2, o);
            }
            if (ln == 0) {
                int rl = hi * 4 + g * 8 + r4;
                sred[rl][wave][0] = ps;
                sred[rl][wave][1] = ps2;
            }
        }
    __syncthreads();
#pragma unroll
    for (int g = 0; g < 4; ++g)
#pragma unroll
        for (int r4 = 0; r4 < 4; ++r4) {
            int i = g * 4 + r4;
            int rl = hi * 4 + g * 8 + r4;
            float s  = sred[rl][0][0] + sred[rl][1][0] + sred[rl][2][0] + sred[rl][3][0];
            float s2 = sred[rl][0][1] + sred[rl][1][1] + sred[rl][2][1] + sred[rl][3][1];
            float m = s * (1.0f / 256.0f);
            float var = fmaxf(s2 * (1.0f / 256.0f) - m * m, 0.0f);
            float rinv = 1.0f / sqrtf(var + 1e-5f);
            size_t base = (size_t)(row0 + rl) * ND + colbase + ln;
#pragma unroll
            for (int nt = 0; nt < 2; ++nt) {
                float v = (acc[nt][i] - m) * rinv * gv[nt] + bv[nt];
                x[base + nt * 32] = v;
                xtb[base + nt * 32] = f2b(v);
            }
        }
}

// ---------------- attention v10 (R14-exact): K staged once per block; V in registers ----------------
__global__ __launch_bounds__(256, 2) void attn3_kernel(const unsigned short* __restrict__ qkv,
                                                       const unsigned short* __restrict__ vt,
                                                       unsigned short* __restrict__ out)
{
    __shared__ __align__(16) unsigned short sP[4][32 * 128];
    __shared__ __align__(16) unsigned short sK[128 * 64];
    const int tid = threadIdx.x;
    const int lane = tid & 63, wave = tid >> 6;
    const int ln = lane & 31, hi = lane >> 5;
    const int h = blockIdx.y, b = blockIdx.z;
    const int q0 = blockIdx.x * 128 + wave * 32;
    const size_t base = (size_t)b * NT * 768;
    const int qoff = h * 64;
    const unsigned short* vbh = vt + (size_t)(b * NH + h) * 64 * NT;

    bf16x8 qf[4];
#pragma unroll
    for (int s = 0; s < 4; ++s)
        qf[s] = *(const bf16x8*)&qkv[base + (size_t)(q0 + ln) * 768 + qoff + s * 16 + hi * 8];

    f32x16 oacc[2] = {};
    f32x16 lacc = {};
    bf16x8 onev;
#pragma unroll
    for (int j = 0; j < 8; ++j) onev[j] = (short)0x3F80;   // bf16 1.0
    const float sc = 0.18033688011112042f;   // 0.125 * log2(e)
    unsigned short* Pw = &sP[wave][0];

    for (int ch = 0; ch < 4; ++ch) {
        const int s0 = ch * 128;
#pragma unroll
        for (int j = 0; j < 4; ++j) {
            int c = wave + 4 * j;
            int rl = c * 8 + (lane >> 3);
            int bg = (lane & 7) ^ (rl & 7);
            gload16(&qkv[base + (size_t)(s0 + rl) * 768 + 256 + qoff + bg * 8],
                    &sK[c * 8 * 64]);
        }
        __syncthreads();
        f32x16 sacc[4] = {};
        __builtin_amdgcn_s_setprio(1);
#pragma unroll
        for (int p = 0; p < 4; ++p)
#pragma unroll
            for (int s = 0; s < 4; ++s) {
                int rk = p * 32 + ln;
                bf16x8 kf = *(const bf16x8*)&sK[rk * 64 + (((s * 2 + hi) ^ (rk & 7)) << 3)];
                sacc[p] = __builtin_amdgcn_mfma_f32_32x32x16_bf16(qf[s], kf, sacc[p], 0, 0, 0);
            }
        __builtin_amdgcn_s_setprio(0);
        bf16x8 vfr[2][4];
#pragma unroll
        for (int ct = 0; ct < 2; ++ct)
#pragma unroll
            for (int s = 0; s < 4; ++s)
                vfr[ct][s] = *(const bf16x8*)&vbh[(size_t)(ct * 32 + ln) * NT + s0 + s * 16 + hi * 8];
#pragma unroll
        for (int i = 0; i < 16; ++i) {
            sacc[0][i] = exp2f(fminf(sacc[0][i] * sc, 80.f));
            sacc[1][i] = exp2f(fminf(sacc[1][i] * sc, 80.f));
            sacc[2][i] = exp2f(fminf(sacc[2][i] * sc, 80.f));
            sacc[3][i] = exp2f(fminf(sacc[3][i] * sc, 80.f));
        }
#pragma unroll
        for (int p = 0; p < 4; ++p) {
            int kb = p * 4 + (ln >> 3), k7 = ln & 7;
#pragma unroll
            for (int i = 0; i < 16; ++i) {
                int q = (i & 3) + 8 * (i >> 2) + 4 * hi;
                Pw[q * 128 + (((kb ^ (q & 7)) << 3) | k7)] = f2b(sacc[p][i]);
            }
        }
        __builtin_amdgcn_s_setprio(1);
#pragma unroll
        for (int s = 0; s < 4; ++s) {
            bf16x8 pf = *(const bf16x8*)&Pw[ln * 128 + (((s * 2 + hi) ^ (ln & 7)) << 3)];
#pragma unroll
            for (int ct = 0; ct < 2; ++ct)
                oacc[ct] = __builtin_amdgcn_mfma_f32_32x32x16_bf16(vfr[ct][s], pf, oacc[ct], 0, 0, 0);
            lacc = __builtin_amdgcn_mfma_f32_32x32x16_bf16(onev, pf, lacc, 0, 0, 0);
        }
        __builtin_amdgcn_s_setprio(0);
#pragma unroll
        for (int ct = 0; ct < 2; ++ct)
#pragma unroll
            for (int s = 0; s < 4; ++s)
                vfr[ct][s] = *(const bf16x8*)&vbh[(size_t)(ct * 32 + ln) * NT + s0 + 64 + s * 16 + hi * 8];
        __builtin_amdgcn_s_setprio(1);
#pragma unroll
        for (int s = 0; s < 4; ++s) {
            bf16x8 pf = *(const bf16x8*)&Pw[ln * 128 + (((8 + s * 2 + hi) ^ (ln & 7)) << 3)];
#pragma unroll
            for (int ct = 0; ct < 2; ++ct)
                oacc[ct] = __builtin_amdgcn_mfma_f32_32x32x16_bf16(vfr[ct][s], pf, oacc[ct], 0, 0, 0);
            lacc = __builtin_amdgcn_mfma_f32_32x32x16_bf16(onev, pf, lacc, 0, 0, 0);
        }
        __builtin_amdgcn_s_setprio(0);
        __syncthreads();   // all waves done with sK before next chunk's staging
    }
    float linv = 1.0f / lacc[0];
    const int q = q0 + ln;
#pragma unroll
    for (int ct = 0; ct < 2; ++ct)
#pragma unroll
        for (int g = 0; g < 4; ++g) {
            unsigned short s4[4];
#pragma unroll
            for (int r4 = 0; r4 < 4; ++r4)
                s4[r4] = f2b(oacc[ct][g * 4 + r4] * linv);
            int d = ct * 32 + g * 8 + 4 * hi;
            *(uint2*)&out[(size_t)(b * NT + q) * ND + qoff + d] = *(uint2*)s4;
        }
}

// ---------------- fuse: xb = bf16(x + eB[b]) -- pure memory-bound add ----------------
__global__ __launch_bounds__(256) void fuse_kernel(const float* __restrict__ eB,
                                                   const float* __restrict__ x,
                                                   unsigned short* __restrict__ xb)
{
    const int row = blockIdx.x;
    const int d = threadIdx.x;
    xb[(size_t)row * ND + d] = f2b(x[(size_t)row * ND + d] + eB[(row >> 9) * ND + d]);
}

// ---------------- unified bf16 MFMA conv: t-tile TT, o-tile ONT*32, wave MT=TT/128 ----------------
template<int CIN, int KS, int TT, int ONT, bool OUT_BF16, bool BN>
__global__ __launch_bounds__(256) void convk_kernel(const unsigned short* __restrict__ inb,
                                                    const unsigned short* __restrict__ wtb,
                                                    const float* __restrict__ bias,
                                                    const float* __restrict__ bng,
                                                    const float* __restrict__ bnb,
                                                    const float* __restrict__ bnm,
                                                    const float* __restrict__ bnv,
                                                    void* __restrict__ out_,
                                                    int T, int COUT)
{
    constexpr int PAD = (KS - 1) / 2;
    constexpr int TEXT = TT + KS - 1;
    constexpr int OTS = ONT * 32;
    constexpr int MT = TT / 128;
    constexpr int BR = KS * OTS;          // B rows
    constexpr int HR = KS - 1;            // halo rows
    __shared__ __align__(16) unsigned short Asb[TEXT * 32];
    __shared__ __align__(16) unsigned short Bsb[BR * 32];
    const int tid = threadIdx.x;
    const int lane = tid & 63, wave = tid >> 6;
    const int ln = lane & 31, hi = lane >> 5;
    const int b = blockIdx.z;
    const int t0 = blockIdx.x * TT;
    const int o0 = blockIdx.y * OTS;
    const int mOff = wave * (MT * 32);
    float* outf = (float*)out_;
    unsigned short* outb = (unsigned short*)out_;
    f32x16 acc[MT][ONT] = {};

    for (int cc = 0; cc < CIN; cc += 32) {
#pragma unroll
        for (int it = 0; it < TT / 64; ++it) {
            int t = PAD + it * 64 + wave * 16 + (lane >> 2);
            int tg = t0 + it * 64 + wave * 16 + (lane >> 2);
            int bg = (lane & 3) ^ SW(t);
            gload16(&inb[((size_t)(b * T) + tg) * CIN + cc + bg * 8],
                    &Asb[(PAD + it * 64 + wave * 16) * 32]);
        }
        if (tid < HR * 4) {
            int hr = tid >> 2, blk = tid & 3;
            int t = (hr < PAD) ? hr : TT + hr;
            int tg = t0 - PAD + t;
            uint4 z = {0u, 0u, 0u, 0u};
            if (tg >= 0 && tg < T)
                z = *(const uint4*)&inb[((size_t)(b * T) + tg) * CIN + cc + blk * 8];
            *(uint4*)&Asb[t * 32 + ((blk ^ SW(t)) << 3)] = z;
        }
#pragma unroll
        for (int c = wave; c < BR / 16; c += 4) {
            int row = c * 16 + (lane >> 2);
            int k = row / OTS, o = row % OTS;
            int bg = (lane & 3) ^ SW(row);
            gload16(&wtb[((size_t)k * COUT + o0 + o) * CIN + cc + bg * 8],
                    &Bsb[c * 16 * 32]);
        }
        __syncthreads();
#pragma unroll
        for (int kh = 0; kh < 2; ++kh) {
            const int kb = kh * 2 + hi;
#pragma unroll
            for (int tap = 0; tap < KS; ++tap) {
                bf16x8 af[MT];
#pragma unroll
                for (int mt = 0; mt < MT; ++mt) {
                    int r = mOff + mt * 32 + ln + tap;
                    af[mt] = *(const bf16x8*)&Asb[r * 32 + ((kb ^ SW(r)) << 3)];
                }
#pragma unroll
                for (int nt = 0; nt < ONT; ++nt) {
                    int rb = tap * OTS + nt * 32 + ln;
                    bf16x8 bfr = *(const bf16x8*)&Bsb[rb * 32 + ((kb ^ SW(rb)) << 3)];
#pragma unroll
                    for (int mt = 0; mt < MT; ++mt)
                        acc[mt][nt] = __builtin_amdgcn_mfma_f32_32x32x16_bf16(
                            af[mt], bfr, acc[mt][nt], 0, 0, 0);
                }
            }
        }
        __syncthreads();
    }
#pragma unroll
    for (int nt = 0; nt < ONT; ++nt) {
        int col = o0 + nt * 32 + ln;
        float bi = bias[col];
        float scv = 1.f, shv = 0.f;
        if (BN) {
            scv = bng[col] / sqrtf(bnv[col] + 1e-5f);
            shv = bnb[col] - bnm[col] * scv;
        }
#pragma unroll
        for (int mt = 0; mt < MT; ++mt)
#pragma unroll
            for (int g = 0; g < 4; ++g)
#pragma unroll
                for (int r4 = 0; r4 < 4; ++r4) {
                    int row = t0 + mOff + mt * 32 + hi * 4 + g * 8 + r4;
                    float v = fmaxf(acc[mt][nt][g * 4 + r4] + bi, 0.f);
                    if (BN) v = v * scv + shv;
                    if (OUT_BF16) outb[((size_t)(b * T) + row) * COUT + col] = f2b(v);
                    else          outf[((size_t)(b * T) + row) * COUT + col] = v;
                }
    }
}

// ---------------- regulated-sequence materialization (bf16 gather) ----------------
__global__ __launch_bounds__(256) void reg_kernel(const unsigned short* __restrict__ xb,
                                                  const int* __restrict__ tok,
                                                  unsigned short* __restrict__ reg)
{
    const int wave = threadIdx.x >> 6, lane = threadIdx.x & 63;
    const int row = blockIdx.x * 4 + wave;
    const int tk = tok[row];
    const int b = row >> 11;
    const int c4 = lane * 4;
    unsigned short s4[4] = {0, 0, 0, 0};
    if (tk >= 0)
        *(uint2*)s4 = *(const uint2*)&xb[((size_t)(b * NT) + tk) * ND + c4];
    *(uint2*)&reg[(size_t)row * ND + c4] = *(uint2*)s4;
}

// ---------------- duration: wave-per-row dot -> dur ----------------
__global__ __launch_bounds__(256) void dur_kernel(const float* __restrict__ h2,
                                                  const float* __restrict__ wo,
                                                  const float* __restrict__ bo,
                                                  int* __restrict__ dur)
{
    const int wave = threadIdx.x >> 6, lane = threadIdx.x & 63;
    const int row = blockIdx.x * 4 + wave;
    const int c4 = lane * 4;
    float4 h = *(const float4*)&h2[(size_t)row * ND + c4];
    float4 w4 = *(const float4*)&wo[c4];
    float s = h.x * w4.x + h.y * w4.y + h.z * w4.z + h.w * w4.w;
#pragma unroll
    for (int o = 1; o < 64; o <<= 1) s += __shfl_xor(s, o);
    if (lane == 0) {
        float d = rintf(expf(s + bo[0]));
        d = fminf(fmaxf(d, 1.0f), 8.0f);
        dur[row] = (int)d;
    }
}

// ---------------- fused scan + token map: parallel block-wide scan ----------------
__global__ __launch_bounds__(256) void scantok_kernel(const int* __restrict__ dur,
                                                      int* __restrict__ tok)
{
    __shared__ int st[NT];
    __shared__ int wsum[4];
    const int b = blockIdx.x, tid = threadIdx.x;
    int v0 = dur[b * NT + 2 * tid];
    int v1 = dur[b * NT + 2 * tid + 1];
    int p = v0 + v1;
    const int lane = tid & 63, w = tid >> 6;
    int x = p;
#pragma unroll
    for (int o = 1; o < 64; o <<= 1) {
        int y = __shfl_up(x, o);
        if (lane >= o) x += y;
    }
    if (lane == 63) wsum[w] = x;
    __syncthreads();
    int add = 0;
#pragma unroll
    for (int k = 0; k < 4; ++k) if (k < w) add += wsum[k];
    int tot = wsum[0] + wsum[1] + wsum[2] + wsum[3];
    int excl = x + add - p;
    st[2 * tid] = excl;
    st[2 * tid + 1] = excl + v0;
    __syncthreads();
    for (int pp = tid; pp < TOUT; pp += 256) {
        int res = -1;
        if (pp < tot) {
            int lo = 0, hi2 = NT - 1;
            while (lo < hi2) {
                int mid = (lo + hi2 + 1) >> 1;
                if (st[mid] <= pp) lo = mid; else hi2 = mid - 1;
            }
            res = lo;
        }
        tok[b * TOUT + pp] = res;
    }
}

// ---------------- decoder conv3: wave-per-output, coalesced ----------------
__global__ __launch_bounds__(256) void conv3_kernel(const unsigned short* __restrict__ in,
                                                    const float* __restrict__ w,
                                                    const float* __restrict__ bias,
                                                    float* __restrict__ out)
{
    const int wave = threadIdx.x >> 6, lane = threadIdx.x & 63;
    const int gid = blockIdx.x * 4 + wave;
    const int b = gid >> 11, t = gid & (TOUT - 1);
    const int c = lane * 2;
    float w0[5], w1[5];
#pragma unroll
    for (int k = 0; k < 5; ++k) { w0[k] = w[c * 5 + k]; w1[k] = w[(c + 1) * 5 + k]; }
    float acc = 0.f;
#pragma unroll
    for (int k = 0; k < 5; ++k) {
        int t2 = t + k - 2;
        if (t2 < 0 || t2 >= TOUT) continue;
        unsigned int u = *(const unsigned int*)&in[((size_t)(b * TOUT) + t2) * 128 + c];
        acc = fmaf(b2f((unsigned short)(u & 0xFFFF)), w0[k], acc);
        acc = fmaf(b2f((unsigned short)(u >> 16)), w1[k], acc);
    }
#pragma unroll
    for (int o = 1; o < 64; o <<= 1) acc += __shfl_xor(acc, o);
    if (lane == 0) out[gid] = acc + bias[0];
}

// ---------------- orchestration ----------------
extern "C" void kernel_launch(void* const* d_in, const int* in_sizes, int n_in,
                              void* d_out, int out_size, void* d_ws, size_t ws_size,
                              hipStream_t stream)
{
    const int*   text    = (const int*)d_in[0];
    const float* emotion = (const float*)d_in[1];
    const float* emb     = (const float*)d_in[2];
    const float* Wqkv    = (const float*)d_in[3];
    const float* bqkv    = (const float*)d_in[4];
    const float* Wo      = (const float*)d_in[5];
    const float* bo      = (const float*)d_in[6];
    const float* W1      = (const float*)d_in[7];
    const float* b1      = (const float*)d_in[8];
    const float* W2      = (const float*)d_in[9];
    const float* b2      = (const float*)d_in[10];
    const float* ln1g    = (const float*)d_in[11];
    const float* ln1b    = (const float*)d_in[12];
    const float* ln2g    = (const float*)d_in[13];
    const float* ln2b    = (const float*)d_in[14];
    const float* We1     = (const float*)d_in[15];
    const float* be1     = (const float*)d_in[16];
    const float* We2     = (const float*)d_in[17];
    const float* be2     = (const float*)d_in[18];
    const float* dp_w1   = (const float*)d_in[19];
    const float* dp_b1   = (const float*)d_in[20];
    const float* dp_g1   = (const float*)d_in[21];
    const float* dp_bt1  = (const float*)d_in[22];
    const float* dp_m1   = (const float*)d_in[23];
    const float* dp_v1   = (const float*)d_in[24];
    const float* dp_w2   = (const float*)d_in[25];
    const float* dp_b2   = (const float*)d_in[26];
    const float* dp_g2   = (const float*)d_in[27];
    const float* dp_bt2  = (const float*)d_in[28];
    const float* dp_m2   = (const float*)d_in[29];
    const float* dp_v2   = (const float*)d_in[30];
    const float* dp_wo   = (const float*)d_in[31];
    const float* dp_bo   = (const float*)d_in[32];
    const float* dec_w3  = (const float*)d_in[37];
    const float* dec_b1  = (const float*)d_in[34];
    const float* dec_b2  = (const float*)d_in[36];
    const float* dec_b3  = (const float*)d_in[38];

    float* ws   = (float*)d_ws;
    float* x    = ws + OFF_X;
    unsigned short* ffhB = (unsigned short*)(ws + OFF_FFH);
    unsigned short* Wbt  = (unsigned short*)(ws + OFF_WBT);
    unsigned short* cw   = (unsigned short*)(ws + OFF_CWT);
    unsigned short* wtbdp1 = cw;
    unsigned short* wtbdp2 = cw + 196608;
    unsigned short* wtb1   = cw + 393216;
    unsigned short* wtb2   = cw + 720896;
    unsigned short* xtb    = cw + 4194304;   // bf16 mirror of x [16384,256]
    unsigned short* qkvB = (unsigned short*)(ws + OFF_QKV);
    unsigned short* vtb  = qkvB + 12582912;
    unsigned short* regB = qkvB;
    float* attb = ws + OFF_ATTN;
    float* prjb = ws + OFF_PROJ;
    unsigned short* attbB = (unsigned short*)attb;
    unsigned short* h1b  = (unsigned short*)attb;
    unsigned short* xbB  = (unsigned short*)attb + 4194304;   // 2nd half of ATTN region
    unsigned short* d1b  = ffhB;
    unsigned short* d2b  = (unsigned short*)attb;
    int*   ip     = (int*)(ws + OFF_INT);
    int*   durb   = ip;
    int*   tokb   = ip + 16384;
    float* eB     = (float*)(ip + 16384 + 65536);   // emotion MLP [32,256]

    const int M = NB * NT;   // 16384

    embed_kernel<<<M, 256, 0, stream>>>(text, emb, x, xtb);
    emo_kernel<<<NB, 256, 0, stream>>>(emotion, We1, be1, We2, be2, eB);
    wqall_kernel<<<dim3(768, 6), 256, 0, stream>>>(Wqkv, Wo, W1, W2, Wbt);
    wtransball_kernel<<<3456, 256, 0, stream>>>(dp_w1, dp_w2,
                                                (const float*)d_in[33], (const float*)d_in[35], cw);

    for (int l = 0; l < NLAYER; ++l) {
        const unsigned short* WQ  = Wbt + (size_t)l * 786432;
        const unsigned short* WO  = WQ + 196608;
        const unsigned short* WF1 = WQ + 262144;
        const unsigned short* WF2 = WQ + 524288;
        gemmbf_kernel<128, false, true, true><<<dim3(6, 128), 256, 0, stream>>>(
            xtb, WQ, bqkv + l * 768, qkvB, vtb, M, 768, 256);
        attn3_kernel<<<dim3(NT / 128, NH, NB), 256, 0, stream>>>(qkvB, vtb, attbB);
        gemmln_kernel<<<M / 32, 256, 0, stream>>>(
            attbB, WO, bo + l * 256, ln1g + l * ND, ln1b + l * ND, x, xtb, 256);
        gemmbf_kernel<128, true, true, false><<<dim3(8, 128), 256, 0, stream>>>(
            xtb, WF1, b1 + l * 1024, ffhB, nullptr, M, 1024, 256);
        gemmln_kernel<<<M / 32, 256, 0, stream>>>(
            ffhB, WF2, b2 + l * 256, ln2g + l * ND, ln2b + l * ND, x, xtb, 1024);
    }

    fuse_kernel<<<M, 256, 0, stream>>>(eB, x, xbB);

    // duration predictor convs: t-tile 128 -> 512 blocks (2+ blocks/CU)
    convk_kernel<256, 3, 128, 2, true, true><<<dim3(4, 4, NB), 256, 0, stream>>>(
        xbB, wtbdp1, dp_b1, dp_g1, dp_bt1, dp_m1, dp_v1, h1b, NT, 256);
    convk_kernel<256, 3, 128, 2, false, true><<<dim3(4, 4, NB), 256, 0, stream>>>(
        h1b, wtbdp2, dp_b2, dp_g2, dp_bt2, dp_m2, dp_v2, prjb, NT, 256);
    dur_kernel<<<M / 4, 256, 0, stream>>>(prjb, dp_wo, dp_bo, durb);
    scantok_kernel<<<NB, 256, 0, stream>>>(durb, tokb);

    // decoder: regulated gather then bf16 MFMA convs
    reg_kernel<<<NB * TOUT / 4, 256, 0, stream>>>(xbB, tokb, regB);
    convk_kernel<256, 5, 256, 2, true, false><<<dim3(TOUT / 256, 4, NB), 256, 0, stream>>>(
        regB, wtb1, dec_b1, nullptr, nullptr, nullptr, nullptr, d1b, TOUT, 256);
    convk_kernel<256, 5, 256, 2, true, false><<<dim3(TOUT / 256, 2, NB), 256, 0, stream>>>(
        d1b, wtb2, dec_b2, nullptr, nullptr, nullptr, nullptr, d2b, TOUT, 128);
    conv3_kernel<<<NB * TOUT / 4, 256, 0, stream>>>(d2b, dec_w3, dec_b3, (float*)d_out);
}